// Round 7
// baseline (291.021 us; speedup 1.0000x reference)
//
#include <hip/hip_runtime.h>
#include <hip/hip_bf16.h>

#define D_MODEL 1024
#define NH 16
#define DK 64
#define S_LEN 2048
#define BATCH 2
#define M_ROWS (BATCH * S_LEN)   // 4096

typedef float    floatx4 __attribute__((ext_vector_type(4)));
typedef _Float16 half8   __attribute__((ext_vector_type(8)));
typedef _Float16 half4v  __attribute__((ext_vector_type(4)));

#define LOG2E 1.4426950408889634f
#define EXPM1 0.36787944117144233f   // exp(-1) = exp2(-LOG2E)

__device__ __forceinline__ half8 ldh8(const _Float16* p) {
    return __builtin_bit_cast(half8, *(const uint4*)p);
}
__device__ __forceinline__ void gld16(const void* g, void* l) {
    __builtin_amdgcn_global_load_lds(
        (const __attribute__((address_space(1))) void*)g,
        (__attribute__((address_space(3))) void*)l, 16, 0, 0);
}
// rte fp32x8 -> fp16x8 (same rounding as the old prep cast path)
__device__ __forceinline__ half8 cvt8(float4 a, float4 b) {
    half8 h;
    h[0] = (_Float16)a.x; h[1] = (_Float16)a.y;
    h[2] = (_Float16)a.z; h[3] = (_Float16)a.w;
    h[4] = (_Float16)b.x; h[5] = (_Float16)b.y;
    h[6] = (_Float16)b.z; h[7] = (_Float16)b.w;
    return h;
}
// swap lanes 0<->1, 2<->3 within each quad (DPP quad_perm(1,0,3,2))
__device__ __forceinline__ float dpp_swap1(float x) {
    return __builtin_bit_cast(float,
        __builtin_amdgcn_mov_dpp(__builtin_bit_cast(int, x), 0xB1, 0xF, 0xF, false));
}
// raw workgroup barrier without the __syncthreads() vmcnt(0) drain
__device__ __forceinline__ void rawbar() {
    __builtin_amdgcn_sched_barrier(0);
    __builtin_amdgcn_s_barrier();
    __builtin_amdgcn_sched_barrier(0);
}

// ---------------------------------------------------------------------------
// mask int32 [S,S] -> bitmask uint64 mb[row][wid].  grid 4096, 16 words/blk.
// (prep's cast work is gone: the gemms now convert fp32 during staging.)
// ---------------------------------------------------------------------------
__global__ __launch_bounds__(256)
void mask_pack(const int* __restrict__ mask, unsigned long long* __restrict__ mb) {
    const int wv_ = threadIdx.x >> 6, lane = threadIdx.x & 63;
#pragma unroll
    for (int i = 0; i < 4; i++) {
        const int gw = blockIdx.x * 16 + wv_ * 4 + i;
        const int row = gw >> 5, wid = gw & 31;
        const int mv = mask[(size_t)row * S_LEN + wid * 64 + lane];
        unsigned long long bal = __ballot(mv != 0);
        if (lane == 0) mb[gw] = bal;
    }
}

// ---------------------------------------------------------------------------
// C = A[M,1024] @ W[1024,1024]^T (+bias), fp16 MFMA, fused fp32->fp16.
// W is ALWAYS read fp32 and reg-staged (global_load_dwordx4 -> rte cvt ->
// ds_write_b128); OUTMODE 1 also reg-stages A from the raw fp32 inputs
// (q/k/v selected by z) -> the prep cast kernel and its 112 MB HBM
// round-trip are eliminated.  OUTMODE 0 keeps gld16 for A (Xh is fp16).
// K-loop schedule (validated round 6, T14-extended): per iter
//   vmcnt(0) gate -> cvt+ds_write tile k -> rawbar -> ds_read frags ->
//   lgkmcnt(0)+rawbar (reads done) -> issue tile k+1 loads -> MFMAs
// so both the global loads AND the cvt/ds_write overlap the MFMA block.
// OUTMODE 0: fp32 row-major out.  OUTMODE 1: fp16 head-major via
// LDS-staged coalesced epilogue; z==0 (Q) pre-scaled; z==2 (V) staged
// transposed -> lands directly in Vt [bh][d][s].
// ---------------------------------------------------------------------------
template <int OUTMODE>
__global__ __launch_bounds__(256)
void gemm_f16(const void* __restrict__ Aq_, const void* __restrict__ Ak_,
              const void* __restrict__ Av_,
              const float* __restrict__ Wq_, const float* __restrict__ Wk_,
              const float* __restrict__ Wv_,
              const float* __restrict__ b0, const float* __restrict__ b1,
              const float* __restrict__ b2, void* __restrict__ Obase,
              void* __restrict__ Obase2) {
    __shared__ __align__(16) _Float16 SM[16384];   // As | Ws ; reused by epilogue
    _Float16* As = SM;
    _Float16* Ws = SM + 8192;
    const int tid = threadIdx.x;
    const int w = tid >> 6, lane = tid & 63;
    const int l15 = lane & 15, q4 = lane >> 4;
    const int z = (OUTMODE == 1) ? blockIdx.z : 0;
    const int m0 = blockIdx.y * 128, n0 = blockIdx.x * 128;
    const int wm = w >> 1, wn = w & 1;

    const float* Af = (OUTMODE == 1)
        ? (const float*)((z == 0) ? Aq_ : (z == 1) ? Ak_ : Av_) : nullptr;
    const _Float16* Ah = (OUTMODE == 0) ? (const _Float16*)Aq_ : nullptr;
    const float* Wf = (z == 0) ? Wq_ : (z == 1) ? Wk_ : Wv_;
    const float* bias = (OUTMODE == 1) ? ((z == 0) ? b0 : (z == 1) ? b1 : b2) : b0;

    int srow[4], sseg[4];
#pragma unroll
    for (int i = 0; i < 4; i++) {
        const int slot = i * 256 + tid;
        srow[i] = slot >> 3;
        sseg[i] = ((slot & 7) ^ (srow[i] & 7)) * 8;
    }

    int aoff[4][2], woff[4][2];
#pragma unroll
    for (int r = 0; r < 4; r++) {
        const int ar = wm * 64 + r * 16 + l15;
        const int wr = wn * 64 + r * 16 + l15;
#pragma unroll
        for (int kc = 0; kc < 2; kc++) {
            aoff[r][kc] = (ar * 8 + ((kc * 4 + q4) ^ (ar & 7))) * 8;
            woff[r][kc] = (wr * 8 + ((kc * 4 + q4) ^ (wr & 7))) * 8;
        }
    }

    floatx4 acc[4][4];
#pragma unroll
    for (int r = 0; r < 4; r++)
#pragma unroll
        for (int c = 0; c < 4; c++) acc[r][c] = (floatx4){0.f, 0.f, 0.f, 0.f};

    float4 ra[4][2], rw[4][2];

    // prologue: issue loads for tile k0=0
    if (OUTMODE == 1) {
#pragma unroll
        for (int i = 0; i < 4; i++) {
            const float* p = &Af[(size_t)(m0 + srow[i]) * 1024 + sseg[i]];
            ra[i][0] = *(const float4*)p;
            ra[i][1] = *(const float4*)(p + 4);
        }
    } else {
#pragma unroll
        for (int i = 0; i < 4; i++)
            gld16(&Ah[(size_t)(m0 + srow[i]) * 1024 + sseg[i]],
                  &As[(i * 256 + w * 64) * 8]);
    }
#pragma unroll
    for (int i = 0; i < 4; i++) {
        const float* p = &Wf[(size_t)(n0 + srow[i]) * 1024 + sseg[i]];
        rw[i][0] = *(const float4*)p;
        rw[i][1] = *(const float4*)(p + 4);
    }

    for (int k0 = 0; k0 < 1024; k0 += 64) {
        // gate: all vmem for tile k0 landed (reg loads + gld16)
        __builtin_amdgcn_sched_barrier(0);
        asm volatile("s_waitcnt vmcnt(0)" ::: "memory");
        // cvt + ds_write tile k0 (reads of k0-64 were barriered done last iter)
        if (OUTMODE == 1) {
#pragma unroll
            for (int i = 0; i < 4; i++)
                *(uint4*)&As[(size_t)(i * 256 + tid) * 8] =
                    __builtin_bit_cast(uint4, cvt8(ra[i][0], ra[i][1]));
        }
#pragma unroll
        for (int i = 0; i < 4; i++)
            *(uint4*)&Ws[(size_t)(i * 256 + tid) * 8] =
                __builtin_bit_cast(uint4, cvt8(rw[i][0], rw[i][1]));
        rawbar();   // tile k0 visible to all waves

        half8 af[4][2], wf[4][2];
#pragma unroll
        for (int r = 0; r < 4; r++)
#pragma unroll
            for (int kc = 0; kc < 2; kc++) {
                af[r][kc] = ldh8(&As[aoff[r][kc]]);
                wf[r][kc] = ldh8(&Ws[woff[r][kc]]);
            }
        // all waves done reading the LDS tile -> safe to overwrite next iter
        asm volatile("s_waitcnt lgkmcnt(0)" ::: "memory");
        rawbar();

        if (k0 < 1024 - 64) {
            const int kn = k0 + 64;
            if (OUTMODE == 1) {
#pragma unroll
                for (int i = 0; i < 4; i++) {
                    const float* p = &Af[(size_t)(m0 + srow[i]) * 1024 + kn + sseg[i]];
                    ra[i][0] = *(const float4*)p;
                    ra[i][1] = *(const float4*)(p + 4);
                }
            } else {
#pragma unroll
                for (int i = 0; i < 4; i++)
                    gld16(&Ah[(size_t)(m0 + srow[i]) * 1024 + kn + sseg[i]],
                          &As[(i * 256 + w * 64) * 8]);
            }
#pragma unroll
            for (int i = 0; i < 4; i++) {
                const float* p = &Wf[(size_t)(n0 + srow[i]) * 1024 + kn + sseg[i]];
                rw[i][0] = *(const float4*)p;
                rw[i][1] = *(const float4*)(p + 4);
            }
        }
        __builtin_amdgcn_sched_barrier(0);   // keep load-issue above the MFMAs

#pragma unroll
        for (int kc = 0; kc < 2; kc++)
#pragma unroll
            for (int r = 0; r < 4; r++)
#pragma unroll
                for (int c = 0; c < 4; c++)
                    acc[r][c] = __builtin_amdgcn_mfma_f32_16x16x32_f16(
                        af[r][kc], wf[c][kc], acc[r][c], 0, 0, 0);
    }

    if (OUTMODE == 0) {
#pragma unroll
        for (int r = 0; r < 4; r++)
#pragma unroll
            for (int c = 0; c < 4; c++) {
                const int n = n0 + wn * 64 + c * 16 + l15;
                const int mbase = m0 + wm * 64 + r * 16 + q4 * 4;
#pragma unroll
                for (int reg = 0; reg < 4; reg++)
                    ((float*)Obase)[(size_t)(mbase + reg) * 1024 + n] =
                        acc[r][c][reg] + bias[n];
            }
    } else {
        const int h0 = n0 >> 6;          // 2 heads per 128-n block column
        const int bB = m0 >> 11;         // batch (tile never crosses: 2048%128==0)
        if (z == 2) {
            // stage transposed E[n][m] (XOR-swizzled 16-B slots)
#pragma unroll
            for (int r = 0; r < 4; r++)
#pragma unroll
                for (int c = 0; c < 4; c++) {
                    const int nl = wn * 64 + c * 16 + l15;
                    const int ml = wm * 64 + r * 16 + q4 * 4;
                    half4v hv;
#pragma unroll
                    for (int reg = 0; reg < 4; reg++)
                        hv[reg] = (_Float16)(acc[r][c][reg] + bias[n0 + nl]);
                    const int seg = ml >> 3, wi = ml & 7;
                    *(half4v*)&SM[nl * 128 + ((seg ^ (nl & 7)) << 3) + wi] = hv;
                }
            __syncthreads();
#pragma unroll
            for (int it = 0; it < 8; it++) {
                const int chunk = it * 256 + tid;
                const int row = chunk >> 4, seg = chunk & 15;   // row=n, seg of m
                half8 v8 = ldh8(&SM[row * 128 + ((seg ^ (row & 7)) << 3)]);
                const int d = row & 63, hh = row >> 6;
                const int s = (m0 & 2047) + seg * 8;
                *(uint4*)&((_Float16*)Obase2)[
                    (((size_t)((bB * 16 + h0 + hh) * 64 + d)) << 11) + s] =
                    __builtin_bit_cast(uint4, v8);
            }
        } else {
            const float sc = (z == 0) ? 0.125f * LOG2E : 1.0f;
            // stage E[m][n] (scalar b16 writes, XOR-swizzled 16-B slots)
#pragma unroll
            for (int r = 0; r < 4; r++)
#pragma unroll
                for (int c = 0; c < 4; c++) {
                    const int nl = wn * 64 + c * 16 + l15;
                    const int seg = nl >> 3, wi = nl & 7;
                    const float bv = bias[n0 + nl];
#pragma unroll
                    for (int reg = 0; reg < 4; reg++) {
                        const int ml = wm * 64 + r * 16 + q4 * 4 + reg;
                        SM[ml * 128 + ((seg ^ (ml & 7)) << 3) + wi] =
                            (_Float16)((acc[r][c][reg] + bv) * sc);
                    }
                }
            __syncthreads();
            _Float16* Oz = (_Float16*)Obase + (size_t)z * M_ROWS * 1024;
#pragma unroll
            for (int it = 0; it < 8; it++) {
                const int chunk = it * 256 + tid;
                const int row = chunk >> 4, seg = chunk & 15;   // row=m, seg of n
                half8 v8 = ldh8(&SM[row * 128 + ((seg ^ (row & 7)) << 3)]);
                const int s = (m0 + row) & 2047;
                const int hh = seg >> 3, d = (seg & 7) * 8;
                *(uint4*)&Oz[(((size_t)((bB * 16 + h0 + hh)) * S_LEN + s) << 6) + d] =
                    __builtin_bit_cast(uint4, v8);
            }
        }
    }
}

// ---------------------------------------------------------------------------
// MFMA flash attention v9 = v8 + mask-word prefetch one j-iter ahead (the 8
// L2 loads were issued mid-QK and consumed ~20 instrs later -> unhidden
// ~300-900cy latency; now they fly over a full iteration).  +~24 VGPR
// (total ~124 <= the (512,4) 128 cap; WRITE_SIZE ~8 MB asserts no spill).
// Grid (S/128, B*H), 512 thr, LDS 68.9 KB -> 2 blocks/CU = 16 waves/CU.
// ---------------------------------------------------------------------------
__global__ __launch_bounds__(512, 4)
void attn_mfma(const _Float16* __restrict__ Qh, const _Float16* __restrict__ Kh,
               const _Float16* __restrict__ Vt, const unsigned long long* __restrict__ mb,
               _Float16* __restrict__ Xh) {
    __shared__ __align__(16) _Float16 Ks[2][64 * 64];   // [half][key][d]  16 KB
    __shared__ __align__(16) _Float16 Vs[2][64 * 64];   // [half][d][key]  16 KB
    __shared__ __align__(16) _Float16 Ps[8][32 * 72];   // per-wave P, 36.9 KB

    const int tid = threadIdx.x;
    const int w = tid >> 6, lane = tid & 63;
    const int z = w >> 2, w4 = w & 3;       // key-half, wave-within-half
    const int t255 = tid & 255;
    const int l15 = lane & 15, q4 = lane >> 4;
    const int bh = blockIdx.y, b = bh >> 4, h = bh & 15;
    const int qb = blockIdx.x * 128 + w4 * 32;
    const int kbase = z * 1024;

    const _Float16* Qg = Qh + ((size_t)bh * S_LEN + qb) * DK;
    const _Float16* Kg = Kh + ((size_t)bh * S_LEN + kbase) * DK;
    const _Float16* Vg = Vt + (size_t)bh * DK * S_LEN + kbase;

    // Q fragments (A-operand), resident all kernel (scale pre-folded in gemm)
    half8 Aq[2][2];
#pragma unroll
    for (int qs = 0; qs < 2; qs++)
#pragma unroll
        for (int ch = 0; ch < 2; ch++)
            Aq[qs][ch] = ldh8(&Qg[(qs * 16 + l15) * DK + ch * 32 + q4 * 8]);

    // staging slots within each 256-thread half
    int grow[2], gseg[2];
#pragma unroll
    for (int i = 0; i < 2; i++) {
        const int slot = i * 256 + t255;
        grow[i] = slot >> 3;
        gseg[i] = ((slot & 7) ^ (grow[i] & 7)) * 8;
    }

    // fragment base offsets (halfs) into swizzled Ks/Vs; full offset =
    // kb[ch] + jt*1024 (jt*1024 folds into the ds_read immediate)
    int kb[2];
#pragma unroll
    for (int ch = 0; ch < 2; ch++)
        kb[ch] = l15 * 64 + (((ch * 4 + q4) ^ (l15 & 7)) * 8);

    // mask word base: row (qb + q4*4), key-half offset folded in.
    // index per (qs,reg,jw) = qs*512 + reg*32 + jw
    const unsigned long long* mrow_p = mb + (size_t)(qb + q4 * 4) * (S_LEN / 64) + z * 16;

    floatx4 O[2][4];
#pragma unroll
    for (int qs = 0; qs < 2; qs++)
#pragma unroll
        for (int nt = 0; nt < 4; nt++) O[qs][nt] = (floatx4){0.f, 0.f, 0.f, 0.f};
    floatx4 lacc[2];
    lacc[0] = (floatx4){0.f, 0.f, 0.f, 0.f};
    lacc[1] = (floatx4){0.f, 0.f, 0.f, 0.f};

    half8 onesB;
#pragma unroll
    for (int i = 0; i < 8; i++) onesB[i] = (_Float16)1.0f;

    const bool evenlane = ((lane & 1) == 0);

    // mask words for iter 0 (prefetched; rotated each iteration)
    unsigned long long mwc[2][4];
#pragma unroll
    for (int qs = 0; qs < 2; qs++)
#pragma unroll
        for (int reg = 0; reg < 4; reg++)
            mwc[qs][reg] = mrow_p[qs * 512 + reg * 32];

    // prologue: stage K_0 then V_0   (FIFO: K,K,V,V)
#pragma unroll
    for (int i = 0; i < 2; i++) {
        const int lb = (i * 256 + w4 * 64) * 8;
        gld16(&Kg[(size_t)grow[i] * DK + gseg[i]], &Ks[z][lb]);
    }
#pragma unroll
    for (int i = 0; i < 2; i++) {
        const int lb = (i * 256 + w4 * 64) * 8;
        gld16(&Vg[(size_t)grow[i] * S_LEN + gseg[i]], &Vs[z][lb]);
    }

    for (int j0 = 0; j0 < 1024; j0 += 64) {
        const int jn = (j0 + 64) & 1023;   // wrap keeps vmcnt schedule uniform
        const int jwn = ((j0 >> 6) + 1) & 15;

        // ---- K gate: my K_j landed (V_j may still fly); then block-wide ----
        __builtin_amdgcn_sched_barrier(0);
        asm volatile("s_waitcnt vmcnt(2)" ::: "memory");
        rawbar();

        // prefetch NEXT iter's mask words (fly over this whole iteration)
        unsigned long long mwn[2][4];
#pragma unroll
        for (int qs = 0; qs < 2; qs++)
#pragma unroll
            for (int reg = 0; reg < 4; reg++)
                mwn[qs][reg] = mrow_p[qs * 512 + reg * 32 + jwn];

        // ---- QK + fused softmax (per-jt: only one floatx4 live) ----
#pragma unroll
        for (int qs = 0; qs < 2; qs++) {
#pragma unroll
            for (int jt = 0; jt < 4; jt++) {
                floatx4 c = (floatx4){0.f, 0.f, 0.f, 0.f};
                __builtin_amdgcn_s_setprio(1);
                c = __builtin_amdgcn_mfma_f32_16x16x32_f16(
                    Aq[qs][0], ldh8(&Ks[z][jt * 1024 + kb[0]]), c, 0, 0, 0);
                c = __builtin_amdgcn_mfma_f32_16x16x32_f16(
                    Aq[qs][1], ldh8(&Ks[z][jt * 1024 + kb[1]]), c, 0, 0, 0);
                __builtin_amdgcn_s_setprio(0);
#pragma unroll
                for (int reg = 0; reg < 4; reg++) {
                    const unsigned ttw =
                        (unsigned)(mwc[qs][reg] >> (jt >= 2 ? 32 : 0)) >> l15;
                    const unsigned sel = ttw & (1u << ((jt & 1) * 16));
                    float p = __builtin_amdgcn_exp2f(c[reg]);
                    p = sel ? p : EXPM1;
                    const float po = dpp_swap1(p);
                    if (evenlane) {
                        *(unsigned*)&Ps[w][(qs * 16 + q4 * 4 + reg) * 72 +
                                           jt * 16 + l15] =
                            __builtin_bit_cast(unsigned,
                                __builtin_amdgcn_cvt_pkrtz(p, po));
                    }
                }
            }
        }

        // ---- Ks consumed block-wide -> prefetch K_{j+1} (flies over PV) ----
        rawbar();
#pragma unroll
        for (int i = 0; i < 2; i++) {
            const int lb = (i * 256 + w4 * 64) * 8;
            gld16(&Kg[(size_t)(jn + grow[i]) * DK + gseg[i]], &Ks[z][lb]);
        }

        // ---- V gate: my V_j landed (K_{j+1} in flight); block-wide ----
        __builtin_amdgcn_sched_barrier(0);
        asm volatile("s_waitcnt vmcnt(2)" ::: "memory");
        rawbar();

        // ---- PV: O[qs] += P[qs] @ V ; Σp via all-ones B ----
#pragma unroll
        for (int qs = 0; qs < 2; qs++) {
            half8 Ap[2];
#pragma unroll
            for (int ch = 0; ch < 2; ch++)
                Ap[ch] = ldh8(&Ps[w][(qs * 16 + l15) * 72 + ch * 32 + q4 * 8]);
            __builtin_amdgcn_s_setprio(1);
            lacc[qs] = __builtin_amdgcn_mfma_f32_16x16x32_f16(Ap[0], onesB, lacc[qs], 0, 0, 0);
            lacc[qs] = __builtin_amdgcn_mfma_f32_16x16x32_f16(Ap[1], onesB, lacc[qs], 0, 0, 0);
#pragma unroll
            for (int nt = 0; nt < 4; nt++) {
                O[qs][nt] = __builtin_amdgcn_mfma_f32_16x16x32_f16(
                    Ap[0], ldh8(&Vs[z][nt * 1024 + kb[0]]), O[qs][nt], 0, 0, 0);
                O[qs][nt] = __builtin_amdgcn_mfma_f32_16x16x32_f16(
                    Ap[1], ldh8(&Vs[z][nt * 1024 + kb[1]]), O[qs][nt], 0, 0, 0);
            }
            __builtin_amdgcn_s_setprio(0);
        }

        // ---- Vs consumed block-wide -> prefetch V_{j+1} (flies over QK) ----
        rawbar();
#pragma unroll
        for (int i = 0; i < 2; i++) {
            const int lb = (i * 256 + w4 * 64) * 8;
            gld16(&Vg[(size_t)grow[i] * S_LEN + jn + gseg[i]], &Vs[z][lb]);
        }

        // rotate mask prefetch
#pragma unroll
        for (int qs = 0; qs < 2; qs++)
#pragma unroll
            for (int reg = 0; reg < 4; reg++)
                mwc[qs][reg] = mwn[qs][reg];
    }
    __builtin_amdgcn_sched_barrier(0);

    // cross-half combine via LDS (reuse Ps region: all P reads are done;
    // the loop's final rawbar ordered the last PV reads before these writes)
    float* Obuf = (float*)&Ps[0][0];                  // [4][32][65] fp32, 33.3 KB
    if (z == 1) {
#pragma unroll
        for (int qs = 0; qs < 2; qs++)
#pragma unroll
            for (int reg = 0; reg < 4; reg++) {
                const int rl = w4 * 32 + qs * 16 + q4 * 4 + reg;
#pragma unroll
                for (int nt = 0; nt < 4; nt++)
                    Obuf[rl * 65 + nt * 16 + l15] = O[qs][nt][reg];
                if (l15 == 0) Obuf[rl * 65 + 64] = lacc[qs][reg];
            }
    }
    __syncthreads();
    if (z == 0) {
#pragma unroll
        for (int qs = 0; qs < 2; qs++)
#pragma unroll
            for (int reg = 0; reg < 4; reg++) {
                const int rl = w4 * 32 + qs * 16 + q4 * 4 + reg;
                const float inv = 1.0f / (lacc[qs][reg] + Obuf[rl * 65 + 64]);
                const int srow = qb + qs * 16 + q4 * 4 + reg;
                _Float16* Xrow = Xh + (size_t)(b * S_LEN + srow) * 1024 + h * DK;
#pragma unroll
                for (int nt = 0; nt < 4; nt++)
                    Xrow[nt * 16 + l15] =
                        (_Float16)((O[qs][nt][reg] + Obuf[rl * 65 + nt * 16 + l15]) * inv);
            }
    }
}

// ---------------------------------------------------------------------------
extern "C" void kernel_launch(void* const* d_in, const int* in_sizes, int n_in,
                              void* d_out, int out_size, void* d_ws, size_t ws_size,
                              hipStream_t stream) {
    const float* q  = (const float*)d_in[0];
    const float* k  = (const float*)d_in[1];
    const float* v  = (const float*)d_in[2];
    const int* mask = (const int*)d_in[3];
    const float* wq = (const float*)d_in[4];
    const float* bq = (const float*)d_in[5];
    const float* wk = (const float*)d_in[6];
    const float* bk = (const float*)d_in[7];
    const float* wv = (const float*)d_in[8];
    const float* bv = (const float*)d_in[9];
    const float* wo = (const float*)d_in[10];
    const float* bo = (const float*)d_in[11];
    float* out = (float*)d_out;

    char* ws = (char*)d_ws;
    const size_t MB = 1u << 20;
    _Float16* Xh   = (_Float16*)(ws + 8 * MB);         // 8 MB (attn out, fp16)
    _Float16* QKVh = (_Float16*)(ws + 32 * MB);        // 2 x 8 MB head-major (Q,K)
    _Float16* Vt   = (_Float16*)(ws + 56 * MB);        // 8 MB
    unsigned long long* mb = (unsigned long long*)(ws + 64 * MB);  // 512 KB

    mask_pack<<<4096, 256, 0, stream>>>(mask, mb);

    gemm_f16<1><<<dim3(8, 32, 3), 256, 0, stream>>>(q, k, v, wq, wk, wv,
                                                    bq, bk, bv, QKVh, Vt);

    attn_mfma<<<dim3(16, 32), 512, 0, stream>>>(QKVh, QKVh + (size_t)M_ROWS * 1024,
                                                Vt, mb, Xh);

    gemm_f16<0><<<dim3(8, 32, 1), 256, 0, stream>>>(Xh, nullptr, nullptr,
                                                    wo, nullptr, nullptr,
                                                    bo, bo, bo, out, nullptr);
}

// Round 8
// 268.356 us; speedup vs baseline: 1.0845x; 1.0845x over previous
//
#include <hip/hip_runtime.h>
#include <hip/hip_bf16.h>

#define D_MODEL 1024
#define NH 16
#define DK 64
#define S_LEN 2048
#define BATCH 2
#define M_ROWS (BATCH * S_LEN)   // 4096

typedef float    floatx4 __attribute__((ext_vector_type(4)));
typedef _Float16 half8   __attribute__((ext_vector_type(8)));
typedef _Float16 half4v  __attribute__((ext_vector_type(4)));

#define LOG2E 1.4426950408889634f
#define EXPM1 0.36787944117144233f   // exp(-1) = exp2(-LOG2E)

__device__ __forceinline__ half8 ldh8(const _Float16* p) {
    return __builtin_bit_cast(half8, *(const uint4*)p);
}
__device__ __forceinline__ void gld16(const void* g, void* l) {
    __builtin_amdgcn_global_load_lds(
        (const __attribute__((address_space(1))) void*)g,
        (__attribute__((address_space(3))) void*)l, 16, 0, 0);
}
// swap lanes 0<->1, 2<->3 within each quad (DPP quad_perm(1,0,3,2))
__device__ __forceinline__ float dpp_swap1(float x) {
    return __builtin_bit_cast(float,
        __builtin_amdgcn_mov_dpp(__builtin_bit_cast(int, x), 0xB1, 0xF, 0xF, false));
}
// raw workgroup barrier without the __syncthreads() vmcnt(0) drain
__device__ __forceinline__ void rawbar() {
    __builtin_amdgcn_sched_barrier(0);
    __builtin_amdgcn_s_barrier();
    __builtin_amdgcn_sched_barrier(0);
}

// ---------------------------------------------------------------------------
// prep: fused fp32->fp16 casts (q,k,v,wq,wk,wv,wo) + mask bit-pack.
// grid (4096, 8), 256 thr.  y 0-2: qkv rows (R=4096); y 3-6: weights
// (R=1024, blocks >=1024 idle); y 7: mask_pack (16 words/block).
// (Round-7 lesson: converting fp32 inside the gemm halves nothing — the
// A/W tiles are re-read 8-32x by other blocks, so fp32 reads cost ~2x the
// amplified traffic.  Pre-casting once is the cheaper total.)
// ---------------------------------------------------------------------------
__global__ __launch_bounds__(256)
void prep(const float* __restrict__ q, const float* __restrict__ k,
          const float* __restrict__ v, const float* __restrict__ wq,
          const float* __restrict__ wk, const float* __restrict__ wv,
          const float* __restrict__ wo, const int* __restrict__ mask,
          _Float16* __restrict__ Ah, _Float16* __restrict__ Wh,
          unsigned long long* __restrict__ mb) {
    const int y = blockIdx.y;
    if (y < 7) {
        if (y >= 3 && blockIdx.x >= 1024) return;   // weights: R=1024
        const float* src = (y == 0) ? q : (y == 1) ? k : (y == 2) ? v :
                           (y == 3) ? wq : (y == 4) ? wk : (y == 5) ? wv : wo;
        _Float16* dst = (y < 3) ? (Ah + (size_t)y * M_ROWS * 1024)
                                : (Wh + (size_t)(y - 3) * 1024 * 1024);
        const size_t idx = ((size_t)blockIdx.x * 256 + threadIdx.x) * 4;
        float4 f = *(const float4*)&src[idx];
        half4v h = {(_Float16)f.x, (_Float16)f.y, (_Float16)f.z, (_Float16)f.w};
        *(half4v*)&dst[idx] = h;
    } else {
        const int wv_ = threadIdx.x >> 6, lane = threadIdx.x & 63;
#pragma unroll
        for (int i = 0; i < 4; i++) {
            const int gw = blockIdx.x * 16 + wv_ * 4 + i;
            const int row = gw >> 5, wid = gw & 31;
            const int mv = mask[(size_t)row * S_LEN + wid * 64 + lane];
            unsigned long long bal = __ballot(mv != 0);
            if (lane == 0) mb[gw] = bal;
        }
    }
}

// ---------------------------------------------------------------------------
// C = A[M,1024] @ W[1024,1024]^T (+bias), fp16 MFMA.
// Tile-ownership XCD swizzle (NEW): with grid (8,32,z) the hardware maps
// xcd = blockIdx.x, so mi = bx*4 + (by&3), ni = by>>2 puts all 8 blocks
// sharing an A-panel on the SAME XCD -> A fetched once per panel instead
// of once per XCD (round-7 counters showed 202 MB FETCH from exactly this
// amplification).  Mapping is bijective on (mi,ni).
// K-loop (validated round 6, issue-early/gate-late): vmcnt(0)+rawbar gate
// -> ds_read frags -> lgkmcnt(0)+rawbar -> issue tile k+1 -> MFMAs.
// OUTMODE 0: fp32 row-major out.  OUTMODE 1: fp16 head-major via
// LDS-staged coalesced epilogue; z==0 (Q) pre-scaled; z==2 (V) staged
// transposed -> lands directly in Vt [bh][d][s].
// ---------------------------------------------------------------------------
template <int OUTMODE>
__global__ __launch_bounds__(256)
void gemm_f16(const _Float16* __restrict__ Abase, const _Float16* __restrict__ Wbase,
              const float* __restrict__ b0, const float* __restrict__ b1,
              const float* __restrict__ b2, void* __restrict__ Obase,
              void* __restrict__ Obase2) {
    __shared__ __align__(16) _Float16 SM[16384];   // As | Ws ; reused by epilogue
    _Float16* As = SM;
    _Float16* Ws = SM + 8192;
    const int tid = threadIdx.x;
    const int w = tid >> 6, lane = tid & 63;
    const int l15 = lane & 15, q4 = lane >> 4;
    const int z = (OUTMODE == 1) ? blockIdx.z : 0;
    // XCD-locality swizzle: same-A blocks share blockIdx.x (= XCD)
    const int mi = blockIdx.x * 4 + (blockIdx.y & 3);
    const int ni = blockIdx.y >> 2;
    const int m0 = mi * 128, n0 = ni * 128;
    const int wm = w >> 1, wn = w & 1;

    const _Float16* A = Abase + (size_t)z * M_ROWS * 1024;
    const _Float16* W = Wbase + (size_t)z * 1024 * 1024;
    const float* bias = (OUTMODE == 1) ? ((z == 0) ? b0 : (z == 1) ? b1 : b2) : b0;

    int srow[4], sseg[4];
#pragma unroll
    for (int i = 0; i < 4; i++) {
        const int slot = i * 256 + tid;
        srow[i] = slot >> 3;
        sseg[i] = ((slot & 7) ^ (srow[i] & 7)) * 8;
    }

    int aoff[4][2], woff[4][2];
#pragma unroll
    for (int r = 0; r < 4; r++) {
        const int ar = wm * 64 + r * 16 + l15;
        const int wr = wn * 64 + r * 16 + l15;
#pragma unroll
        for (int kc = 0; kc < 2; kc++) {
            aoff[r][kc] = (ar * 8 + ((kc * 4 + q4) ^ (ar & 7))) * 8;
            woff[r][kc] = (wr * 8 + ((kc * 4 + q4) ^ (wr & 7))) * 8;
        }
    }

    floatx4 acc[4][4];
#pragma unroll
    for (int r = 0; r < 4; r++)
#pragma unroll
        for (int c = 0; c < 4; c++) acc[r][c] = (floatx4){0.f, 0.f, 0.f, 0.f};

    // prologue: stage tile k0=0
#pragma unroll
    for (int i = 0; i < 4; i++) {
        const int lb = (i * 256 + w * 64) * 8;
        gld16(&A[(size_t)(m0 + srow[i]) * 1024 + sseg[i]], &As[lb]);
        gld16(&W[(size_t)(n0 + srow[i]) * 1024 + sseg[i]], &Ws[lb]);
    }

    for (int k0 = 0; k0 < 1024; k0 += 64) {
        // gate: tile k0 landed (loads flew over previous MFMA block)
        __builtin_amdgcn_sched_barrier(0);
        asm volatile("s_waitcnt vmcnt(0)" ::: "memory");
        rawbar();

        half8 af[4][2], wf[4][2];
#pragma unroll
        for (int r = 0; r < 4; r++)
#pragma unroll
            for (int kc = 0; kc < 2; kc++) {
                af[r][kc] = ldh8(&As[aoff[r][kc]]);
                wf[r][kc] = ldh8(&Ws[woff[r][kc]]);
            }
        // all waves done reading the LDS tile -> safe to overwrite
        asm volatile("s_waitcnt lgkmcnt(0)" ::: "memory");
        rawbar();

        if (k0 < 1024 - 64) {
#pragma unroll
            for (int i = 0; i < 4; i++) {
                const int lb = (i * 256 + w * 64) * 8;
                gld16(&A[(size_t)(m0 + srow[i]) * 1024 + (k0 + 64) + sseg[i]], &As[lb]);
                gld16(&W[(size_t)(n0 + srow[i]) * 1024 + (k0 + 64) + sseg[i]], &Ws[lb]);
            }
        }
        __builtin_amdgcn_sched_barrier(0);   // keep stage-issue above the MFMAs

#pragma unroll
        for (int kc = 0; kc < 2; kc++)
#pragma unroll
            for (int r = 0; r < 4; r++)
#pragma unroll
                for (int c = 0; c < 4; c++)
                    acc[r][c] = __builtin_amdgcn_mfma_f32_16x16x32_f16(
                        af[r][kc], wf[c][kc], acc[r][c], 0, 0, 0);
    }

    if (OUTMODE == 0) {
#pragma unroll
        for (int r = 0; r < 4; r++)
#pragma unroll
            for (int c = 0; c < 4; c++) {
                const int n = n0 + wn * 64 + c * 16 + l15;
                const int mbase = m0 + wm * 64 + r * 16 + q4 * 4;
#pragma unroll
                for (int reg = 0; reg < 4; reg++)
                    ((float*)Obase)[(size_t)(mbase + reg) * 1024 + n] =
                        acc[r][c][reg] + bias[n];
            }
    } else {
        const int h0 = n0 >> 6;          // 2 heads per 128-n block column
        const int bB = m0 >> 11;         // batch (tile never crosses: 2048%128==0)
        if (z == 2) {
            // stage transposed E[n][m] (XOR-swizzled 16-B slots)
#pragma unroll
            for (int r = 0; r < 4; r++)
#pragma unroll
                for (int c = 0; c < 4; c++) {
                    const int nl = wn * 64 + c * 16 + l15;
                    const int ml = wm * 64 + r * 16 + q4 * 4;
                    half4v hv;
#pragma unroll
                    for (int reg = 0; reg < 4; reg++)
                        hv[reg] = (_Float16)(acc[r][c][reg] + bias[n0 + nl]);
                    const int seg = ml >> 3, wi = ml & 7;
                    *(half4v*)&SM[nl * 128 + ((seg ^ (nl & 7)) << 3) + wi] = hv;
                }
            __syncthreads();
#pragma unroll
            for (int it = 0; it < 8; it++) {
                const int chunk = it * 256 + tid;
                const int row = chunk >> 4, seg = chunk & 15;   // row=n, seg of m
                half8 v8 = ldh8(&SM[row * 128 + ((seg ^ (row & 7)) << 3)]);
                const int d = row & 63, hh = row >> 6;
                const int s = (m0 & 2047) + seg * 8;
                *(uint4*)&((_Float16*)Obase2)[
                    (((size_t)((bB * 16 + h0 + hh) * 64 + d)) << 11) + s] =
                    __builtin_bit_cast(uint4, v8);
            }
        } else {
            const float sc = (z == 0) ? 0.125f * LOG2E : 1.0f;
            // stage E[m][n] (scalar b16 writes, XOR-swizzled 16-B slots)
#pragma unroll
            for (int r = 0; r < 4; r++)
#pragma unroll
                for (int c = 0; c < 4; c++) {
                    const int nl = wn * 64 + c * 16 + l15;
                    const int seg = nl >> 3, wi = nl & 7;
                    const float bv = bias[n0 + nl];
#pragma unroll
                    for (int reg = 0; reg < 4; reg++) {
                        const int ml = wm * 64 + r * 16 + q4 * 4 + reg;
                        SM[ml * 128 + ((seg ^ (ml & 7)) << 3) + wi] =
                            (_Float16)((acc[r][c][reg] + bv) * sc);
                    }
                }
            __syncthreads();
            _Float16* Oz = (_Float16*)Obase + (size_t)z * M_ROWS * 1024;
#pragma unroll
            for (int it = 0; it < 8; it++) {
                const int chunk = it * 256 + tid;
                const int row = chunk >> 4, seg = chunk & 15;   // row=m, seg of n
                half8 v8 = ldh8(&SM[row * 128 + ((seg ^ (row & 7)) << 3)]);
                const int s = (m0 + row) & 2047;
                const int hh = seg >> 3, d = (seg & 7) * 8;
                *(uint4*)&Oz[(((size_t)((bB * 16 + h0 + hh)) * S_LEN + s) << 6) + d] =
                    __builtin_bit_cast(uint4, v8);
            }
        }
    }
}

// ---------------------------------------------------------------------------
// MFMA flash attention v9: in-block key-split + counted-vmcnt K/V pipeline
// + setprio + mask-word prefetch one j-iter ahead.  (Ran clean round 7.)
// Grid (S/128, B*H), 512 thr, LDS 68.9 KB -> 2 blocks/CU = 16 waves/CU.
// ---------------------------------------------------------------------------
__global__ __launch_bounds__(512, 4)
void attn_mfma(const _Float16* __restrict__ Qh, const _Float16* __restrict__ Kh,
               const _Float16* __restrict__ Vt, const unsigned long long* __restrict__ mb,
               _Float16* __restrict__ Xh) {
    __shared__ __align__(16) _Float16 Ks[2][64 * 64];   // [half][key][d]  16 KB
    __shared__ __align__(16) _Float16 Vs[2][64 * 64];   // [half][d][key]  16 KB
    __shared__ __align__(16) _Float16 Ps[8][32 * 72];   // per-wave P, 36.9 KB

    const int tid = threadIdx.x;
    const int w = tid >> 6, lane = tid & 63;
    const int z = w >> 2, w4 = w & 3;       // key-half, wave-within-half
    const int t255 = tid & 255;
    const int l15 = lane & 15, q4 = lane >> 4;
    const int bh = blockIdx.y, b = bh >> 4, h = bh & 15;
    const int qb = blockIdx.x * 128 + w4 * 32;
    const int kbase = z * 1024;

    const _Float16* Qg = Qh + ((size_t)bh * S_LEN + qb) * DK;
    const _Float16* Kg = Kh + ((size_t)bh * S_LEN + kbase) * DK;
    const _Float16* Vg = Vt + (size_t)bh * DK * S_LEN + kbase;

    // Q fragments (A-operand), resident all kernel (scale pre-folded in gemm)
    half8 Aq[2][2];
#pragma unroll
    for (int qs = 0; qs < 2; qs++)
#pragma unroll
        for (int ch = 0; ch < 2; ch++)
            Aq[qs][ch] = ldh8(&Qg[(qs * 16 + l15) * DK + ch * 32 + q4 * 8]);

    // staging slots within each 256-thread half
    int grow[2], gseg[2];
#pragma unroll
    for (int i = 0; i < 2; i++) {
        const int slot = i * 256 + t255;
        grow[i] = slot >> 3;
        gseg[i] = ((slot & 7) ^ (grow[i] & 7)) * 8;
    }

    // fragment base offsets (halfs) into swizzled Ks/Vs; full offset =
    // kb[ch] + jt*1024 (jt*1024 folds into the ds_read immediate)
    int kb[2];
#pragma unroll
    for (int ch = 0; ch < 2; ch++)
        kb[ch] = l15 * 64 + (((ch * 4 + q4) ^ (l15 & 7)) * 8);

    // mask word base: row (qb + q4*4), key-half offset folded in.
    // index per (qs,reg,jw) = qs*512 + reg*32 + jw
    const unsigned long long* mrow_p = mb + (size_t)(qb + q4 * 4) * (S_LEN / 64) + z * 16;

    floatx4 O[2][4];
#pragma unroll
    for (int qs = 0; qs < 2; qs++)
#pragma unroll
        for (int nt = 0; nt < 4; nt++) O[qs][nt] = (floatx4){0.f, 0.f, 0.f, 0.f};
    floatx4 lacc[2];
    lacc[0] = (floatx4){0.f, 0.f, 0.f, 0.f};
    lacc[1] = (floatx4){0.f, 0.f, 0.f, 0.f};

    half8 onesB;
#pragma unroll
    for (int i = 0; i < 8; i++) onesB[i] = (_Float16)1.0f;

    const bool evenlane = ((lane & 1) == 0);

    // mask words for iter 0 (prefetched; rotated each iteration)
    unsigned long long mwc[2][4];
#pragma unroll
    for (int qs = 0; qs < 2; qs++)
#pragma unroll
        for (int reg = 0; reg < 4; reg++)
            mwc[qs][reg] = mrow_p[qs * 512 + reg * 32];

    // prologue: stage K_0 then V_0   (FIFO: K,K,V,V)
#pragma unroll
    for (int i = 0; i < 2; i++) {
        const int lb = (i * 256 + w4 * 64) * 8;
        gld16(&Kg[(size_t)grow[i] * DK + gseg[i]], &Ks[z][lb]);
    }
#pragma unroll
    for (int i = 0; i < 2; i++) {
        const int lb = (i * 256 + w4 * 64) * 8;
        gld16(&Vg[(size_t)grow[i] * S_LEN + gseg[i]], &Vs[z][lb]);
    }

    for (int j0 = 0; j0 < 1024; j0 += 64) {
        const int jn = (j0 + 64) & 1023;   // wrap keeps vmcnt schedule uniform
        const int jwn = ((j0 >> 6) + 1) & 15;

        // ---- K gate: my K_j landed (V_j may still fly); then block-wide ----
        __builtin_amdgcn_sched_barrier(0);
        asm volatile("s_waitcnt vmcnt(2)" ::: "memory");
        rawbar();

        // prefetch NEXT iter's mask words (fly over this whole iteration)
        unsigned long long mwn[2][4];
#pragma unroll
        for (int qs = 0; qs < 2; qs++)
#pragma unroll
            for (int reg = 0; reg < 4; reg++)
                mwn[qs][reg] = mrow_p[qs * 512 + reg * 32 + jwn];

        // ---- QK + fused softmax (per-jt: only one floatx4 live) ----
#pragma unroll
        for (int qs = 0; qs < 2; qs++) {
#pragma unroll
            for (int jt = 0; jt < 4; jt++) {
                floatx4 c = (floatx4){0.f, 0.f, 0.f, 0.f};
                __builtin_amdgcn_s_setprio(1);
                c = __builtin_amdgcn_mfma_f32_16x16x32_f16(
                    Aq[qs][0], ldh8(&Ks[z][jt * 1024 + kb[0]]), c, 0, 0, 0);
                c = __builtin_amdgcn_mfma_f32_16x16x32_f16(
                    Aq[qs][1], ldh8(&Ks[z][jt * 1024 + kb[1]]), c, 0, 0, 0);
                __builtin_amdgcn_s_setprio(0);
#pragma unroll
                for (int reg = 0; reg < 4; reg++) {
                    const unsigned ttw =
                        (unsigned)(mwc[qs][reg] >> (jt >= 2 ? 32 : 0)) >> l15;
                    const unsigned sel = ttw & (1u << ((jt & 1) * 16));
                    float p = __builtin_amdgcn_exp2f(c[reg]);
                    p = sel ? p : EXPM1;
                    const float po = dpp_swap1(p);
                    if (evenlane) {
                        *(unsigned*)&Ps[w][(qs * 16 + q4 * 4 + reg) * 72 +
                                           jt * 16 + l15] =
                            __builtin_bit_cast(unsigned,
                                __builtin_amdgcn_cvt_pkrtz(p, po));
                    }
                }
            }
        }

        // ---- Ks consumed block-wide -> prefetch K_{j+1} (flies over PV) ----
        rawbar();
#pragma unroll
        for (int i = 0; i < 2; i++) {
            const int lb = (i * 256 + w4 * 64) * 8;
            gld16(&Kg[(size_t)(jn + grow[i]) * DK + gseg[i]], &Ks[z][lb]);
        }

        // ---- V gate: my V_j landed (K_{j+1} in flight); block-wide ----
        __builtin_amdgcn_sched_barrier(0);
        asm volatile("s_waitcnt vmcnt(2)" ::: "memory");
        rawbar();

        // ---- PV: O[qs] += P[qs] @ V ; Σp via all-ones B ----
#pragma unroll
        for (int qs = 0; qs < 2; qs++) {
            half8 Ap[2];
#pragma unroll
            for (int ch = 0; ch < 2; ch++)
                Ap[ch] = ldh8(&Ps[w][(qs * 16 + l15) * 72 + ch * 32 + q4 * 8]);
            __builtin_amdgcn_s_setprio(1);
            lacc[qs] = __builtin_amdgcn_mfma_f32_16x16x32_f16(Ap[0], onesB, lacc[qs], 0, 0, 0);
            lacc[qs] = __builtin_amdgcn_mfma_f32_16x16x32_f16(Ap[1], onesB, lacc[qs], 0, 0, 0);
#pragma unroll
            for (int nt = 0; nt < 4; nt++) {
                O[qs][nt] = __builtin_amdgcn_mfma_f32_16x16x32_f16(
                    Ap[0], ldh8(&Vs[z][nt * 1024 + kb[0]]), O[qs][nt], 0, 0, 0);
                O[qs][nt] = __builtin_amdgcn_mfma_f32_16x16x32_f16(
                    Ap[1], ldh8(&Vs[z][nt * 1024 + kb[1]]), O[qs][nt], 0, 0, 0);
            }
            __builtin_amdgcn_s_setprio(0);
        }

        // ---- Vs consumed block-wide -> prefetch V_{j+1} (flies over QK) ----
        rawbar();
#pragma unroll
        for (int i = 0; i < 2; i++) {
            const int lb = (i * 256 + w4 * 64) * 8;
            gld16(&Vg[(size_t)grow[i] * S_LEN + jn + gseg[i]], &Vs[z][lb]);
        }

        // rotate mask prefetch
#pragma unroll
        for (int qs = 0; qs < 2; qs++)
#pragma unroll
            for (int reg = 0; reg < 4; reg++)
                mwc[qs][reg] = mwn[qs][reg];
    }
    __builtin_amdgcn_sched_barrier(0);

    // cross-half combine via LDS (reuse Ps region: all P reads are done;
    // the loop's final rawbar ordered the last PV reads before these writes)
    float* Obuf = (float*)&Ps[0][0];                  // [4][32][65] fp32, 33.3 KB
    if (z == 1) {
#pragma unroll
        for (int qs = 0; qs < 2; qs++)
#pragma unroll
            for (int reg = 0; reg < 4; reg++) {
                const int rl = w4 * 32 + qs * 16 + q4 * 4 + reg;
#pragma unroll
                for (int nt = 0; nt < 4; nt++)
                    Obuf[rl * 65 + nt * 16 + l15] = O[qs][nt][reg];
                if (l15 == 0) Obuf[rl * 65 + 64] = lacc[qs][reg];
            }
    }
    __syncthreads();
    if (z == 0) {
#pragma unroll
        for (int qs = 0; qs < 2; qs++)
#pragma unroll
            for (int reg = 0; reg < 4; reg++) {
                const int rl = w4 * 32 + qs * 16 + q4 * 4 + reg;
                const float inv = 1.0f / (lacc[qs][reg] + Obuf[rl * 65 + 64]);
                const int srow = qb + qs * 16 + q4 * 4 + reg;
                _Float16* Xrow = Xh + (size_t)(b * S_LEN + srow) * 1024 + h * DK;
#pragma unroll
                for (int nt = 0; nt < 4; nt++)
                    Xrow[nt * 16 + l15] =
                        (_Float16)((O[qs][nt][reg] + Obuf[rl * 65 + nt * 16 + l15]) * inv);
            }
    }
}

// ---------------------------------------------------------------------------
extern "C" void kernel_launch(void* const* d_in, const int* in_sizes, int n_in,
                              void* d_out, int out_size, void* d_ws, size_t ws_size,
                              hipStream_t stream) {
    const float* q  = (const float*)d_in[0];
    const float* k  = (const float*)d_in[1];
    const float* v  = (const float*)d_in[2];
    const int* mask = (const int*)d_in[3];
    const float* wq = (const float*)d_in[4];
    const float* bq = (const float*)d_in[5];
    const float* wk = (const float*)d_in[6];
    const float* bk = (const float*)d_in[7];
    const float* wv = (const float*)d_in[8];
    const float* bv = (const float*)d_in[9];
    const float* wo = (const float*)d_in[10];
    const float* bo = (const float*)d_in[11];
    float* out = (float*)d_out;

    char* ws = (char*)d_ws;
    const size_t MB = 1u << 20;
    _Float16* Wh   = (_Float16*)ws;                    // 4 x 2 MB (wq,wk,wv,wo)
    _Float16* Ah   = (_Float16*)(ws + 8 * MB);         // 3 x 8 MB (q,k,v fp16)
    _Float16* QKVh = (_Float16*)(ws + 32 * MB);        // 2 x 8 MB head-major (Q,K)
    _Float16* Vt   = (_Float16*)(ws + 56 * MB);        // 8 MB
    unsigned long long* mb = (unsigned long long*)(ws + 64 * MB);  // 512 KB
    _Float16* Xh   = Ah;                               // reuse q slot (8 MB)

    prep<<<dim3(4096, 8), 256, 0, stream>>>(q, k, v, wq, wk, wv, wo, mask,
                                            Ah, Wh, mb);

    gemm_f16<1><<<dim3(8, 32, 3), 256, 0, stream>>>(Ah, Wh, bq, bk, bv, QKVh, Vt);

    attn_mfma<<<dim3(16, 32), 512, 0, stream>>>(QKVh, QKVh + (size_t)M_ROWS * 1024,
                                                Vt, mb, Xh);

    gemm_f16<0><<<dim3(8, 32, 1), 256, 0, stream>>>(Xh, Wh + (size_t)3 * 1024 * 1024,
                                                    bo, bo, bo, out, nullptr);
}

// Round 9
// 266.679 us; speedup vs baseline: 1.0913x; 1.0063x over previous
//
#include <hip/hip_runtime.h>
#include <hip/hip_bf16.h>

#define D_MODEL 1024
#define NH 16
#define DK 64
#define S_LEN 2048
#define BATCH 2
#define M_ROWS (BATCH * S_LEN)   // 4096

typedef float    floatx4 __attribute__((ext_vector_type(4)));
typedef _Float16 half8   __attribute__((ext_vector_type(8)));
typedef _Float16 half4v  __attribute__((ext_vector_type(4)));

#define LOG2E 1.4426950408889634f
#define EXPM1 0.36787944117144233f   // exp(-1) = exp2(-LOG2E)

__device__ __forceinline__ half8 ldh8(const _Float16* p) {
    return __builtin_bit_cast(half8, *(const uint4*)p);
}
__device__ __forceinline__ void gld16(const void* g, void* l) {
    __builtin_amdgcn_global_load_lds(
        (const __attribute__((address_space(1))) void*)g,
        (__attribute__((address_space(3))) void*)l, 16, 0, 0);
}
// swap lanes 0<->1, 2<->3 within each quad (DPP quad_perm(1,0,3,2))
__device__ __forceinline__ float dpp_swap1(float x) {
    return __builtin_bit_cast(float,
        __builtin_amdgcn_mov_dpp(__builtin_bit_cast(int, x), 0xB1, 0xF, 0xF, false));
}
// raw workgroup barrier without the __syncthreads() vmcnt(0) drain
__device__ __forceinline__ void rawbar() {
    __builtin_amdgcn_sched_barrier(0);
    __builtin_amdgcn_s_barrier();
    __builtin_amdgcn_sched_barrier(0);
}

// ---------------------------------------------------------------------------
// prep: fused fp32->fp16 casts (q,k,v,wq,wk,wv,wo) + mask bit-pack.
// grid (4096, 8), 256 thr.  y 0-2: qkv rows (R=4096); y 3-6: weights
// (R=1024, blocks >=1024 idle); y 7: mask_pack (16 words/block).
// ---------------------------------------------------------------------------
__global__ __launch_bounds__(256)
void prep(const float* __restrict__ q, const float* __restrict__ k,
          const float* __restrict__ v, const float* __restrict__ wq,
          const float* __restrict__ wk, const float* __restrict__ wv,
          const float* __restrict__ wo, const int* __restrict__ mask,
          _Float16* __restrict__ Ah, _Float16* __restrict__ Wh,
          unsigned long long* __restrict__ mb) {
    const int y = blockIdx.y;
    if (y < 7) {
        if (y >= 3 && blockIdx.x >= 1024) return;   // weights: R=1024
        const float* src = (y == 0) ? q : (y == 1) ? k : (y == 2) ? v :
                           (y == 3) ? wq : (y == 4) ? wk : (y == 5) ? wv : wo;
        _Float16* dst = (y < 3) ? (Ah + (size_t)y * M_ROWS * 1024)
                                : (Wh + (size_t)(y - 3) * 1024 * 1024);
        const size_t idx = ((size_t)blockIdx.x * 256 + threadIdx.x) * 4;
        float4 f = *(const float4*)&src[idx];
        half4v h = {(_Float16)f.x, (_Float16)f.y, (_Float16)f.z, (_Float16)f.w};
        *(half4v*)&dst[idx] = h;
    } else {
        const int wv_ = threadIdx.x >> 6, lane = threadIdx.x & 63;
#pragma unroll
        for (int i = 0; i < 4; i++) {
            const int gw = blockIdx.x * 16 + wv_ * 4 + i;
            const int row = gw >> 5, wid = gw & 31;
            const int mv = mask[(size_t)row * S_LEN + wid * 64 + lane];
            unsigned long long bal = __ballot(mv != 0);
            if (lane == 0) mb[gw] = bal;
        }
    }
}

// ---------------------------------------------------------------------------
// C = A[M,1024] @ W[1024,1024]^T (+bias), fp16 MFMA.  Tile 128m x 64n (was
// 128x128): round-7 counters showed OccupancyPercent 17.8% with neither
// VGPR nor LDS limiting -> GRID-starved (gemm<0> was 1 block/CU).  Halving
// the n-tile doubles the grid (gemm<1> 768->1536 blocks = 6/CU, gemm<0>
// 256->512 = 2/CU), halves acc VGPRs, and each n-tile is exactly one head.
// K-loop (validated round 6, issue-early/gate-late): vmcnt(0)+rawbar gate
// -> ds_read frags -> lgkmcnt(0)+rawbar -> issue tile k+1 -> MFMAs.
// 4 waves as 2m x 2n; per wave 64m x 32n, acc[4][2].
// OUTMODE 0: fp32 row-major out.  OUTMODE 1: fp16 head-major via
// LDS-staged coalesced epilogue; z==0 (Q) pre-scaled; z==2 (V) staged
// transposed -> lands directly in Vt [bh][d][s].  No XCD swizzle (round-8
// A/B: it regressed ~9 us; GEMM is latency-bound, L3 absorbs the reuse).
// ---------------------------------------------------------------------------
template <int OUTMODE>
__global__ __launch_bounds__(256)
void gemm_f16(const _Float16* __restrict__ Abase, const _Float16* __restrict__ Wbase,
              const float* __restrict__ b0, const float* __restrict__ b1,
              const float* __restrict__ b2, void* __restrict__ Obase,
              void* __restrict__ Obase2) {
    __shared__ __align__(16) _Float16 SM[12288];   // As(8K) | Ws(4K) halfs = 24 KB
    _Float16* As = SM;                              // [128][64]
    _Float16* Ws = SM + 8192;                       // [64][64]
    const int tid = threadIdx.x;
    const int w = tid >> 6, lane = tid & 63;
    const int l15 = lane & 15, q4 = lane >> 4;
    const int z = (OUTMODE == 1) ? blockIdx.z : 0;
    const int m0 = blockIdx.y * 128, n0 = blockIdx.x * 64;
    const int wm = w >> 1, wn = w & 1;

    const _Float16* A = Abase + (size_t)z * M_ROWS * 1024;
    const _Float16* W = Wbase + (size_t)z * 1024 * 1024;
    const float* bias = (OUTMODE == 1) ? ((z == 0) ? b0 : (z == 1) ? b1 : b2) : b0;

    // staging slots: A 4/thread (rows 0..127), W 2/thread (rows 0..63)
    int srow[4], sseg[4];
#pragma unroll
    for (int i = 0; i < 4; i++) {
        const int slot = i * 256 + tid;
        srow[i] = slot >> 3;
        sseg[i] = ((slot & 7) ^ (srow[i] & 7)) * 8;
    }

    int aoff[4][2], woff[2][2];
#pragma unroll
    for (int r = 0; r < 4; r++) {
        const int ar = wm * 64 + r * 16 + l15;
#pragma unroll
        for (int kc = 0; kc < 2; kc++)
            aoff[r][kc] = (ar * 8 + ((kc * 4 + q4) ^ (ar & 7))) * 8;
    }
#pragma unroll
    for (int c = 0; c < 2; c++) {
        const int wr = wn * 32 + c * 16 + l15;
#pragma unroll
        for (int kc = 0; kc < 2; kc++)
            woff[c][kc] = (wr * 8 + ((kc * 4 + q4) ^ (wr & 7))) * 8;
    }

    floatx4 acc[4][2];
#pragma unroll
    for (int r = 0; r < 4; r++)
#pragma unroll
        for (int c = 0; c < 2; c++) acc[r][c] = (floatx4){0.f, 0.f, 0.f, 0.f};

    // prologue: stage tile k0=0   (A: 4 gld16, W: 2 gld16)
#pragma unroll
    for (int i = 0; i < 4; i++)
        gld16(&A[(size_t)(m0 + srow[i]) * 1024 + sseg[i]],
              &As[(i * 256 + w * 64) * 8]);
#pragma unroll
    for (int i = 0; i < 2; i++)
        gld16(&W[(size_t)(n0 + srow[i]) * 1024 + sseg[i]],
              &Ws[(i * 256 + w * 64) * 8]);

    for (int k0 = 0; k0 < 1024; k0 += 64) {
        // gate: tile k0 landed (loads flew over previous MFMA block)
        __builtin_amdgcn_sched_barrier(0);
        asm volatile("s_waitcnt vmcnt(0)" ::: "memory");
        rawbar();

        half8 af[4][2], wf[2][2];
#pragma unroll
        for (int r = 0; r < 4; r++)
#pragma unroll
            for (int kc = 0; kc < 2; kc++)
                af[r][kc] = ldh8(&As[aoff[r][kc]]);
#pragma unroll
        for (int c = 0; c < 2; c++)
#pragma unroll
            for (int kc = 0; kc < 2; kc++)
                wf[c][kc] = ldh8(&Ws[woff[c][kc]]);
        // all waves done reading the LDS tile -> safe to overwrite
        asm volatile("s_waitcnt lgkmcnt(0)" ::: "memory");
        rawbar();

        if (k0 < 1024 - 64) {
#pragma unroll
            for (int i = 0; i < 4; i++)
                gld16(&A[(size_t)(m0 + srow[i]) * 1024 + (k0 + 64) + sseg[i]],
                      &As[(i * 256 + w * 64) * 8]);
#pragma unroll
            for (int i = 0; i < 2; i++)
                gld16(&W[(size_t)(n0 + srow[i]) * 1024 + (k0 + 64) + sseg[i]],
                      &Ws[(i * 256 + w * 64) * 8]);
        }
        __builtin_amdgcn_sched_barrier(0);   // keep stage-issue above the MFMAs

#pragma unroll
        for (int kc = 0; kc < 2; kc++)
#pragma unroll
            for (int r = 0; r < 4; r++)
#pragma unroll
                for (int c = 0; c < 2; c++)
                    acc[r][c] = __builtin_amdgcn_mfma_f32_16x16x32_f16(
                        af[r][kc], wf[c][kc], acc[r][c], 0, 0, 0);
    }

    if (OUTMODE == 0) {
#pragma unroll
        for (int r = 0; r < 4; r++)
#pragma unroll
            for (int c = 0; c < 2; c++) {
                const int n = n0 + wn * 32 + c * 16 + l15;
                const int mbase = m0 + wm * 64 + r * 16 + q4 * 4;
#pragma unroll
                for (int reg = 0; reg < 4; reg++)
                    ((float*)Obase)[(size_t)(mbase + reg) * 1024 + n] =
                        acc[r][c][reg] + bias[n];
            }
    } else {
        const int h0 = n0 >> 6;          // exactly one head per n-tile
        const int bB = m0 >> 11;         // batch (tile never crosses: 2048%128==0)
        if (z == 2) {
            // stage transposed E[n(64)][m(128)] (XOR-swizzled 16-B slots)
#pragma unroll
            for (int r = 0; r < 4; r++)
#pragma unroll
                for (int c = 0; c < 2; c++) {
                    const int nl = wn * 32 + c * 16 + l15;
                    const int ml = wm * 64 + r * 16 + q4 * 4;
                    half4v hv;
#pragma unroll
                    for (int reg = 0; reg < 4; reg++)
                        hv[reg] = (_Float16)(acc[r][c][reg] + bias[n0 + nl]);
                    const int seg = ml >> 3, wi = ml & 7;
                    *(half4v*)&SM[nl * 128 + ((seg ^ (nl & 7)) << 3) + wi] = hv;
                }
            __syncthreads();
#pragma unroll
            for (int it = 0; it < 4; it++) {
                const int chunk = it * 256 + tid;
                const int row = chunk >> 4, seg = chunk & 15;   // row=n(d), seg of m
                half8 v8 = ldh8(&SM[row * 128 + ((seg ^ (row & 7)) << 3)]);
                const int s = (m0 & 2047) + seg * 8;
                *(uint4*)&((_Float16*)Obase2)[
                    (((size_t)((bB * 16 + h0) * 64 + row)) << 11) + s] =
                    __builtin_bit_cast(uint4, v8);
            }
        } else {
            const float sc = (z == 0) ? 0.125f * LOG2E : 1.0f;
            // stage E[m(128)][n(64)] (scalar b16 writes, XOR-swizzled 16-B slots)
#pragma unroll
            for (int r = 0; r < 4; r++)
#pragma unroll
                for (int c = 0; c < 2; c++) {
                    const int nl = wn * 32 + c * 16 + l15;
                    const int seg = nl >> 3, wi = nl & 7;
                    const float bv = bias[n0 + nl];
#pragma unroll
                    for (int reg = 0; reg < 4; reg++) {
                        const int ml = wm * 64 + r * 16 + q4 * 4 + reg;
                        SM[ml * 64 + ((seg ^ (ml & 7)) << 3) + wi] =
                            (_Float16)((acc[r][c][reg] + bv) * sc);
                    }
                }
            __syncthreads();
            _Float16* Oz = (_Float16*)Obase + (size_t)z * M_ROWS * 1024;
#pragma unroll
            for (int it = 0; it < 4; it++) {
                const int chunk = it * 256 + tid;
                const int row = chunk >> 3, seg = chunk & 7;   // row=m, seg of n
                half8 v8 = ldh8(&SM[row * 64 + ((seg ^ (row & 7)) << 3)]);
                const int s = (m0 + row) & 2047;
                *(uint4*)&Oz[(((size_t)(bB * 16 + h0) * S_LEN + s) << 6) + seg * 8] =
                    __builtin_bit_cast(uint4, v8);
            }
        }
    }
}

// ---------------------------------------------------------------------------
// MFMA flash attention v8 (round-6 exact): in-block key-split +
// counted-vmcnt K/V pipeline + setprio.  (Round-8's mask prefetch reverted:
// +1.3 us and a 2 MB spill.)
// Grid (S/128, B*H), 512 thr, LDS 68.9 KB -> 2 blocks/CU = 16 waves/CU.
// ---------------------------------------------------------------------------
__global__ __launch_bounds__(512, 4)
void attn_mfma(const _Float16* __restrict__ Qh, const _Float16* __restrict__ Kh,
               const _Float16* __restrict__ Vt, const unsigned long long* __restrict__ mb,
               _Float16* __restrict__ Xh) {
    __shared__ __align__(16) _Float16 Ks[2][64 * 64];   // [half][key][d]  16 KB
    __shared__ __align__(16) _Float16 Vs[2][64 * 64];   // [half][d][key]  16 KB
    __shared__ __align__(16) _Float16 Ps[8][32 * 72];   // per-wave P, 36.9 KB

    const int tid = threadIdx.x;
    const int w = tid >> 6, lane = tid & 63;
    const int z = w >> 2, w4 = w & 3;       // key-half, wave-within-half
    const int t255 = tid & 255;
    const int l15 = lane & 15, q4 = lane >> 4;
    const int bh = blockIdx.y, b = bh >> 4, h = bh & 15;
    const int qb = blockIdx.x * 128 + w4 * 32;
    const int kbase = z * 1024;

    const _Float16* Qg = Qh + ((size_t)bh * S_LEN + qb) * DK;
    const _Float16* Kg = Kh + ((size_t)bh * S_LEN + kbase) * DK;
    const _Float16* Vg = Vt + (size_t)bh * DK * S_LEN + kbase;

    // Q fragments (A-operand), resident all kernel (scale pre-folded in gemm)
    half8 Aq[2][2];
#pragma unroll
    for (int qs = 0; qs < 2; qs++)
#pragma unroll
        for (int ch = 0; ch < 2; ch++)
            Aq[qs][ch] = ldh8(&Qg[(qs * 16 + l15) * DK + ch * 32 + q4 * 8]);

    // staging slots within each 256-thread half
    int grow[2], gseg[2];
#pragma unroll
    for (int i = 0; i < 2; i++) {
        const int slot = i * 256 + t255;
        grow[i] = slot >> 3;
        gseg[i] = ((slot & 7) ^ (grow[i] & 7)) * 8;
    }

    // fragment base offsets (halfs) into swizzled Ks/Vs; full offset =
    // kb[ch] + jt*1024 (jt*1024 folds into the ds_read immediate)
    int kb[2];
#pragma unroll
    for (int ch = 0; ch < 2; ch++)
        kb[ch] = l15 * 64 + (((ch * 4 + q4) ^ (l15 & 7)) * 8);

    // mask word base: row (qb + q4*4), key-half offset folded in.
    // index per (qs,reg,jw) = qs*512 + reg*32 + jw
    const unsigned long long* mrow_p = mb + (size_t)(qb + q4 * 4) * (S_LEN / 64) + z * 16;

    floatx4 O[2][4];
#pragma unroll
    for (int qs = 0; qs < 2; qs++)
#pragma unroll
        for (int nt = 0; nt < 4; nt++) O[qs][nt] = (floatx4){0.f, 0.f, 0.f, 0.f};
    floatx4 lacc[2];
    lacc[0] = (floatx4){0.f, 0.f, 0.f, 0.f};
    lacc[1] = (floatx4){0.f, 0.f, 0.f, 0.f};

    half8 onesB;
#pragma unroll
    for (int i = 0; i < 8; i++) onesB[i] = (_Float16)1.0f;

    const bool evenlane = ((lane & 1) == 0);

    // prologue: stage K_0 then V_0   (FIFO: K,K,V,V)
#pragma unroll
    for (int i = 0; i < 2; i++) {
        const int lb = (i * 256 + w4 * 64) * 8;
        gld16(&Kg[(size_t)grow[i] * DK + gseg[i]], &Ks[z][lb]);
    }
#pragma unroll
    for (int i = 0; i < 2; i++) {
        const int lb = (i * 256 + w4 * 64) * 8;
        gld16(&Vg[(size_t)grow[i] * S_LEN + gseg[i]], &Vs[z][lb]);
    }

    for (int j0 = 0; j0 < 1024; j0 += 64) {
        const int jn = (j0 + 64) & 1023;   // wrap keeps vmcnt schedule uniform
        const int jw = j0 >> 6;

        // ---- K gate: my K_j landed (V_j may still fly); then block-wide ----
        __builtin_amdgcn_sched_barrier(0);
        asm volatile("s_waitcnt vmcnt(2)" ::: "memory");
        rawbar();

        // ---- QK + fused softmax (per-jt: only one floatx4 live) ----
#pragma unroll
        for (int qs = 0; qs < 2; qs++) {
            unsigned long long mw[4];
#pragma unroll
            for (int jt = 0; jt < 4; jt++) {
                floatx4 c = (floatx4){0.f, 0.f, 0.f, 0.f};
                __builtin_amdgcn_s_setprio(1);
                c = __builtin_amdgcn_mfma_f32_16x16x32_f16(
                    Aq[qs][0], ldh8(&Ks[z][jt * 1024 + kb[0]]), c, 0, 0, 0);
                c = __builtin_amdgcn_mfma_f32_16x16x32_f16(
                    Aq[qs][1], ldh8(&Ks[z][jt * 1024 + kb[1]]), c, 0, 0, 0);
                __builtin_amdgcn_s_setprio(0);
                if (jt == 0) {
#pragma unroll
                    for (int reg = 0; reg < 4; reg++)
                        mw[reg] = mrow_p[qs * 512 + reg * 32 + jw];
                }
#pragma unroll
                for (int reg = 0; reg < 4; reg++) {
                    const unsigned ttw =
                        (unsigned)(mw[reg] >> (jt >= 2 ? 32 : 0)) >> l15;
                    const unsigned sel = ttw & (1u << ((jt & 1) * 16));
                    float p = __builtin_amdgcn_exp2f(c[reg]);
                    p = sel ? p : EXPM1;
                    const float po = dpp_swap1(p);
                    if (evenlane) {
                        *(unsigned*)&Ps[w][(qs * 16 + q4 * 4 + reg) * 72 +
                                           jt * 16 + l15] =
                            __builtin_bit_cast(unsigned,
                                __builtin_amdgcn_cvt_pkrtz(p, po));
                    }
                }
            }
        }

        // ---- Ks consumed block-wide -> prefetch K_{j+1} (flies over PV) ----
        rawbar();
#pragma unroll
        for (int i = 0; i < 2; i++) {
            const int lb = (i * 256 + w4 * 64) * 8;
            gld16(&Kg[(size_t)(jn + grow[i]) * DK + gseg[i]], &Ks[z][lb]);
        }

        // ---- V gate: my V_j landed (K_{j+1} in flight); block-wide ----
        __builtin_amdgcn_sched_barrier(0);
        asm volatile("s_waitcnt vmcnt(2)" ::: "memory");
        rawbar();

        // ---- PV: O[qs] += P[qs] @ V ; Σp via all-ones B ----
#pragma unroll
        for (int qs = 0; qs < 2; qs++) {
            half8 Ap[2];
#pragma unroll
            for (int ch = 0; ch < 2; ch++)
                Ap[ch] = ldh8(&Ps[w][(qs * 16 + l15) * 72 + ch * 32 + q4 * 8]);
            __builtin_amdgcn_s_setprio(1);
            lacc[qs] = __builtin_amdgcn_mfma_f32_16x16x32_f16(Ap[0], onesB, lacc[qs], 0, 0, 0);
            lacc[qs] = __builtin_amdgcn_mfma_f32_16x16x32_f16(Ap[1], onesB, lacc[qs], 0, 0, 0);
#pragma unroll
            for (int nt = 0; nt < 4; nt++) {
                O[qs][nt] = __builtin_amdgcn_mfma_f32_16x16x32_f16(
                    Ap[0], ldh8(&Vs[z][nt * 1024 + kb[0]]), O[qs][nt], 0, 0, 0);
                O[qs][nt] = __builtin_amdgcn_mfma_f32_16x16x32_f16(
                    Ap[1], ldh8(&Vs[z][nt * 1024 + kb[1]]), O[qs][nt], 0, 0, 0);
            }
            __builtin_amdgcn_s_setprio(0);
        }

        // ---- Vs consumed block-wide -> prefetch V_{j+1} (flies over QK) ----
        rawbar();
#pragma unroll
        for (int i = 0; i < 2; i++) {
            const int lb = (i * 256 + w4 * 64) * 8;
            gld16(&Vg[(size_t)grow[i] * S_LEN + jn + gseg[i]], &Vs[z][lb]);
        }
    }
    __builtin_amdgcn_sched_barrier(0);

    // cross-half combine via LDS (reuse Ps region: all P reads are done;
    // the loop's final rawbar ordered the last PV reads before these writes)
    float* Obuf = (float*)&Ps[0][0];                  // [4][32][65] fp32, 33.3 KB
    if (z == 1) {
#pragma unroll
        for (int qs = 0; qs < 2; qs++)
#pragma unroll
            for (int reg = 0; reg < 4; reg++) {
                const int rl = w4 * 32 + qs * 16 + q4 * 4 + reg;
#pragma unroll
                for (int nt = 0; nt < 4; nt++)
                    Obuf[rl * 65 + nt * 16 + l15] = O[qs][nt][reg];
                if (l15 == 0) Obuf[rl * 65 + 64] = lacc[qs][reg];
            }
    }
    __syncthreads();
    if (z == 0) {
#pragma unroll
        for (int qs = 0; qs < 2; qs++)
#pragma unroll
            for (int reg = 0; reg < 4; reg++) {
                const int rl = w4 * 32 + qs * 16 + q4 * 4 + reg;
                const float inv = 1.0f / (lacc[qs][reg] + Obuf[rl * 65 + 64]);
                const int srow = qb + qs * 16 + q4 * 4 + reg;
                _Float16* Xrow = Xh + (size_t)(b * S_LEN + srow) * 1024 + h * DK;
#pragma unroll
                for (int nt = 0; nt < 4; nt++)
                    Xrow[nt * 16 + l15] =
                        (_Float16)((O[qs][nt][reg] + Obuf[rl * 65 + nt * 16 + l15]) * inv);
            }
    }
}

// ---------------------------------------------------------------------------
extern "C" void kernel_launch(void* const* d_in, const int* in_sizes, int n_in,
                              void* d_out, int out_size, void* d_ws, size_t ws_size,
                              hipStream_t stream) {
    const float* q  = (const float*)d_in[0];
    const float* k  = (const float*)d_in[1];
    const float* v  = (const float*)d_in[2];
    const int* mask = (const int*)d_in[3];
    const float* wq = (const float*)d_in[4];
    const float* bq = (const float*)d_in[5];
    const float* wk = (const float*)d_in[6];
    const float* bk = (const float*)d_in[7];
    const float* wv = (const float*)d_in[8];
    const float* bv = (const float*)d_in[9];
    const float* wo = (const float*)d_in[10];
    const float* bo = (const float*)d_in[11];
    float* out = (float*)d_out;

    char* ws = (char*)d_ws;
    const size_t MB = 1u << 20;
    _Float16* Wh   = (_Float16*)ws;                    // 4 x 2 MB (wq,wk,wv,wo)
    _Float16* Ah   = (_Float16*)(ws + 8 * MB);         // 3 x 8 MB (q,k,v fp16)
    _Float16* QKVh = (_Float16*)(ws + 32 * MB);        // 2 x 8 MB head-major (Q,K)
    _Float16* Vt   = (_Float16*)(ws + 56 * MB);        // 8 MB
    unsigned long long* mb = (unsigned long long*)(ws + 64 * MB);  // 512 KB
    _Float16* Xh   = Ah;                               // reuse q slot (8 MB)

    prep<<<dim3(4096, 8), 256, 0, stream>>>(q, k, v, wq, wk, wv, wo, mask,
                                            Ah, Wh, mb);

    gemm_f16<1><<<dim3(16, 32, 3), 256, 0, stream>>>(Ah, Wh, bq, bk, bv, QKVh, Vt);

    attn_mfma<<<dim3(16, 32), 512, 0, stream>>>(QKVh, QKVh + (size_t)M_ROWS * 1024,
                                                Vt, mb, Xh);

    gemm_f16<0><<<dim3(16, 32), 256, 0, stream>>>(Xh, Wh + (size_t)3 * 1024 * 1024,
                                                  bo, bo, bo, out, nullptr);
}

// Round 10
// 250.958 us; speedup vs baseline: 1.1596x; 1.0626x over previous
//
#include <hip/hip_runtime.h>
#include <hip/hip_bf16.h>

#define D_MODEL 1024
#define NH 16
#define DK 64
#define S_LEN 2048
#define BATCH 2
#define M_ROWS (BATCH * S_LEN)   // 4096

typedef float    floatx4 __attribute__((ext_vector_type(4)));
typedef _Float16 half8   __attribute__((ext_vector_type(8)));
typedef _Float16 half4v  __attribute__((ext_vector_type(4)));

#define LOG2E 1.4426950408889634f
#define EXPM1 0.36787944117144233f   // exp(-1) = exp2(-LOG2E)

__device__ __forceinline__ half8 ldh8(const _Float16* p) {
    return __builtin_bit_cast(half8, *(const uint4*)p);
}
__device__ __forceinline__ void gld16(const void* g, void* l) {
    __builtin_amdgcn_global_load_lds(
        (const __attribute__((address_space(1))) void*)g,
        (__attribute__((address_space(3))) void*)l, 16, 0, 0);
}
// swap lanes 0<->1, 2<->3 within each quad (DPP quad_perm(1,0,3,2))
__device__ __forceinline__ float dpp_swap1(float x) {
    return __builtin_bit_cast(float,
        __builtin_amdgcn_mov_dpp(__builtin_bit_cast(int, x), 0xB1, 0xF, 0xF, false));
}
// raw workgroup barrier without the __syncthreads() vmcnt(0) drain
__device__ __forceinline__ void rawbar() {
    __builtin_amdgcn_sched_barrier(0);
    __builtin_amdgcn_s_barrier();
    __builtin_amdgcn_sched_barrier(0);
}

// ---------------------------------------------------------------------------
// prep: fused fp32->fp16 casts (q,k,v,wq,wk,wv,wo) + mask bit-pack.
// grid (4096, 8), 256 thr.  y 0-2: qkv rows (R=4096); y 3-6: weights
// (R=1024, blocks >=1024 idle); y 7: mask_pack (16 words/block).
// ---------------------------------------------------------------------------
__global__ __launch_bounds__(256)
void prep(const float* __restrict__ q, const float* __restrict__ k,
          const float* __restrict__ v, const float* __restrict__ wq,
          const float* __restrict__ wk, const float* __restrict__ wv,
          const float* __restrict__ wo, const int* __restrict__ mask,
          _Float16* __restrict__ Ah, _Float16* __restrict__ Wh,
          unsigned long long* __restrict__ mb) {
    const int y = blockIdx.y;
    if (y < 7) {
        if (y >= 3 && blockIdx.x >= 1024) return;   // weights: R=1024
        const float* src = (y == 0) ? q : (y == 1) ? k : (y == 2) ? v :
                           (y == 3) ? wq : (y == 4) ? wk : (y == 5) ? wv : wo;
        _Float16* dst = (y < 3) ? (Ah + (size_t)y * M_ROWS * 1024)
                                : (Wh + (size_t)(y - 3) * 1024 * 1024);
        const size_t idx = ((size_t)blockIdx.x * 256 + threadIdx.x) * 4;
        float4 f = *(const float4*)&src[idx];
        half4v h = {(_Float16)f.x, (_Float16)f.y, (_Float16)f.z, (_Float16)f.w};
        *(half4v*)&dst[idx] = h;
    } else {
        const int wv_ = threadIdx.x >> 6, lane = threadIdx.x & 63;
#pragma unroll
        for (int i = 0; i < 4; i++) {
            const int gw = blockIdx.x * 16 + wv_ * 4 + i;
            const int row = gw >> 5, wid = gw & 31;
            const int mv = mask[(size_t)row * S_LEN + wid * 64 + lane];
            unsigned long long bal = __ballot(mv != 0);
            if (lane == 0) mb[gw] = bal;
        }
    }
}

// ---------------------------------------------------------------------------
// C = A[M,1024] @ W[1024,1024]^T (+bias), fp16 MFMA.  128x128 tile (round-6
// best).  NEW: chunked XCD swizzle — each XCD owns 4m x 4n super-tiles of
// 16 blocks, so the chunk working set (4 A panels + 4 W bands = 2 MB) is
// L2-resident on ONE XCD and BOTH operands stay local.  (Round-8's row
// swizzle failed because it traded pre-existing W locality for A locality;
// this keeps both.)  Bijective decode from the hardware linear id.
// K-loop (validated round 6, issue-early/gate-late): vmcnt(0)+rawbar gate
// -> ds_read frags -> lgkmcnt(0)+rawbar -> issue tile k+1 -> MFMAs.
// OUTMODE 0: fp32 row-major out.  OUTMODE 1: fp16 head-major via
// LDS-staged coalesced epilogue; z==0 (Q) pre-scaled; z==2 (V) staged
// transposed -> lands directly in Vt [bh][d][s].
// ---------------------------------------------------------------------------
template <int OUTMODE>
__global__ __launch_bounds__(256)
void gemm_f16(const _Float16* __restrict__ Abase, const _Float16* __restrict__ Wbase,
              const float* __restrict__ b0, const float* __restrict__ b1,
              const float* __restrict__ b2, void* __restrict__ Obase,
              void* __restrict__ Obase2) {
    __shared__ __align__(16) _Float16 SM[16384];   // As | Ws ; reused by epilogue
    _Float16* As = SM;
    _Float16* Ws = SM + 8192;
    const int tid = threadIdx.x;
    const int w = tid >> 6, lane = tid & 63;
    const int l15 = lane & 15, q4 = lane >> 4;

    // chunked XCD swizzle: hardware xcd = linear_id % 8; one chunk = 16
    // blocks (4m x 4n) all with the same id%8, consecutive slots.
    const int id = blockIdx.x + (blockIdx.y << 3) +
                   ((OUTMODE == 1) ? ((int)blockIdx.z << 8) : 0);
    const int xcd = id & 7, slot = id >> 3;
    const int chunk = slot >> 4, t = slot & 15;
    const int g = chunk * 8 + xcd;          // global chunk index
    const int z = (OUTMODE == 1) ? (g >> 4) : 0;
    const int cz = g & 15;                  // chunk within z: 8 m-chunks x 2 n-chunks
    const int mi = (cz & 7) * 4 + (t >> 2);
    const int ni = (cz >> 3) * 4 + (t & 3);
    const int m0 = mi * 128, n0 = ni * 128;
    const int wm = w >> 1, wn = w & 1;

    const _Float16* A = Abase + (size_t)z * M_ROWS * 1024;
    const _Float16* W = Wbase + (size_t)z * 1024 * 1024;
    const float* bias = (OUTMODE == 1) ? ((z == 0) ? b0 : (z == 1) ? b1 : b2) : b0;

    int srow[4], sseg[4];
#pragma unroll
    for (int i = 0; i < 4; i++) {
        const int slot2 = i * 256 + tid;
        srow[i] = slot2 >> 3;
        sseg[i] = ((slot2 & 7) ^ (srow[i] & 7)) * 8;
    }

    int aoff[4][2], woff[4][2];
#pragma unroll
    for (int r = 0; r < 4; r++) {
        const int ar = wm * 64 + r * 16 + l15;
        const int wr = wn * 64 + r * 16 + l15;
#pragma unroll
        for (int kc = 0; kc < 2; kc++) {
            aoff[r][kc] = (ar * 8 + ((kc * 4 + q4) ^ (ar & 7))) * 8;
            woff[r][kc] = (wr * 8 + ((kc * 4 + q4) ^ (wr & 7))) * 8;
        }
    }

    floatx4 acc[4][4];
#pragma unroll
    for (int r = 0; r < 4; r++)
#pragma unroll
        for (int c = 0; c < 4; c++) acc[r][c] = (floatx4){0.f, 0.f, 0.f, 0.f};

    // prologue: stage tile k0=0
#pragma unroll
    for (int i = 0; i < 4; i++) {
        const int lb = (i * 256 + w * 64) * 8;
        gld16(&A[(size_t)(m0 + srow[i]) * 1024 + sseg[i]], &As[lb]);
        gld16(&W[(size_t)(n0 + srow[i]) * 1024 + sseg[i]], &Ws[lb]);
    }

    for (int k0 = 0; k0 < 1024; k0 += 64) {
        // gate: tile k0 landed (loads flew over previous MFMA block)
        __builtin_amdgcn_sched_barrier(0);
        asm volatile("s_waitcnt vmcnt(0)" ::: "memory");
        rawbar();

        half8 af[4][2], wf[4][2];
#pragma unroll
        for (int r = 0; r < 4; r++)
#pragma unroll
            for (int kc = 0; kc < 2; kc++) {
                af[r][kc] = ldh8(&As[aoff[r][kc]]);
                wf[r][kc] = ldh8(&Ws[woff[r][kc]]);
            }
        // all waves done reading the LDS tile -> safe to overwrite
        asm volatile("s_waitcnt lgkmcnt(0)" ::: "memory");
        rawbar();

        if (k0 < 1024 - 64) {
#pragma unroll
            for (int i = 0; i < 4; i++) {
                const int lb = (i * 256 + w * 64) * 8;
                gld16(&A[(size_t)(m0 + srow[i]) * 1024 + (k0 + 64) + sseg[i]], &As[lb]);
                gld16(&W[(size_t)(n0 + srow[i]) * 1024 + (k0 + 64) + sseg[i]], &Ws[lb]);
            }
        }
        __builtin_amdgcn_sched_barrier(0);   // keep stage-issue above the MFMAs

#pragma unroll
        for (int kc = 0; kc < 2; kc++)
#pragma unroll
            for (int r = 0; r < 4; r++)
#pragma unroll
                for (int c = 0; c < 4; c++)
                    acc[r][c] = __builtin_amdgcn_mfma_f32_16x16x32_f16(
                        af[r][kc], wf[c][kc], acc[r][c], 0, 0, 0);
    }

    if (OUTMODE == 0) {
#pragma unroll
        for (int r = 0; r < 4; r++)
#pragma unroll
            for (int c = 0; c < 4; c++) {
                const int n = n0 + wn * 64 + c * 16 + l15;
                const int mbase = m0 + wm * 64 + r * 16 + q4 * 4;
#pragma unroll
                for (int reg = 0; reg < 4; reg++)
                    ((float*)Obase)[(size_t)(mbase + reg) * 1024 + n] =
                        acc[r][c][reg] + bias[n];
            }
    } else {
        const int h0 = n0 >> 6;          // 2 heads per 128-n block column
        const int bB = m0 >> 11;         // batch (tile never crosses: 2048%128==0)
        if (z == 2) {
            // stage transposed E[n][m] (XOR-swizzled 16-B slots)
#pragma unroll
            for (int r = 0; r < 4; r++)
#pragma unroll
                for (int c = 0; c < 4; c++) {
                    const int nl = wn * 64 + c * 16 + l15;
                    const int ml = wm * 64 + r * 16 + q4 * 4;
                    half4v hv;
#pragma unroll
                    for (int reg = 0; reg < 4; reg++)
                        hv[reg] = (_Float16)(acc[r][c][reg] + bias[n0 + nl]);
                    const int seg = ml >> 3, wi = ml & 7;
                    *(half4v*)&SM[nl * 128 + ((seg ^ (nl & 7)) << 3) + wi] = hv;
                }
            __syncthreads();
#pragma unroll
            for (int it = 0; it < 8; it++) {
                const int chunk2 = it * 256 + tid;
                const int row = chunk2 >> 4, seg = chunk2 & 15;   // row=n, seg of m
                half8 v8 = ldh8(&SM[row * 128 + ((seg ^ (row & 7)) << 3)]);
                const int d = row & 63, hh = row >> 6;
                const int s = (m0 & 2047) + seg * 8;
                *(uint4*)&((_Float16*)Obase2)[
                    (((size_t)((bB * 16 + h0 + hh) * 64 + d)) << 11) + s] =
                    __builtin_bit_cast(uint4, v8);
            }
        } else {
            const float sc = (z == 0) ? 0.125f * LOG2E : 1.0f;
            // stage E[m][n] (scalar b16 writes, XOR-swizzled 16-B slots)
#pragma unroll
            for (int r = 0; r < 4; r++)
#pragma unroll
                for (int c = 0; c < 4; c++) {
                    const int nl = wn * 64 + c * 16 + l15;
                    const int seg = nl >> 3, wi = nl & 7;
                    const float bv = bias[n0 + nl];
#pragma unroll
                    for (int reg = 0; reg < 4; reg++) {
                        const int ml = wm * 64 + r * 16 + q4 * 4 + reg;
                        SM[ml * 128 + ((seg ^ (ml & 7)) << 3) + wi] =
                            (_Float16)((acc[r][c][reg] + bv) * sc);
                    }
                }
            __syncthreads();
            _Float16* Oz = (_Float16*)Obase + (size_t)z * M_ROWS * 1024;
#pragma unroll
            for (int it = 0; it < 8; it++) {
                const int chunk2 = it * 256 + tid;
                const int row = chunk2 >> 4, seg = chunk2 & 15;   // row=m, seg of n
                half8 v8 = ldh8(&SM[row * 128 + ((seg ^ (row & 7)) << 3)]);
                const int s = (m0 + row) & 2047;
                const int hh = seg >> 3, d = (seg & 7) * 8;
                *(uint4*)&Oz[(((size_t)((bB * 16 + h0 + hh)) * S_LEN + s) << 6) + d] =
                    __builtin_bit_cast(uint4, v8);
            }
        }
    }
}

// ---------------------------------------------------------------------------
// MFMA flash attention v8 (round-6 exact): in-block key-split +
// counted-vmcnt K/V pipeline + setprio.
// Grid (S/128, B*H), 512 thr, LDS 68.9 KB -> 2 blocks/CU = 16 waves/CU.
// ---------------------------------------------------------------------------
__global__ __launch_bounds__(512, 4)
void attn_mfma(const _Float16* __restrict__ Qh, const _Float16* __restrict__ Kh,
               const _Float16* __restrict__ Vt, const unsigned long long* __restrict__ mb,
               _Float16* __restrict__ Xh) {
    __shared__ __align__(16) _Float16 Ks[2][64 * 64];   // [half][key][d]  16 KB
    __shared__ __align__(16) _Float16 Vs[2][64 * 64];   // [half][d][key]  16 KB
    __shared__ __align__(16) _Float16 Ps[8][32 * 72];   // per-wave P, 36.9 KB

    const int tid = threadIdx.x;
    const int w = tid >> 6, lane = tid & 63;
    const int z = w >> 2, w4 = w & 3;       // key-half, wave-within-half
    const int t255 = tid & 255;
    const int l15 = lane & 15, q4 = lane >> 4;
    const int bh = blockIdx.y, b = bh >> 4, h = bh & 15;
    const int qb = blockIdx.x * 128 + w4 * 32;
    const int kbase = z * 1024;

    const _Float16* Qg = Qh + ((size_t)bh * S_LEN + qb) * DK;
    const _Float16* Kg = Kh + ((size_t)bh * S_LEN + kbase) * DK;
    const _Float16* Vg = Vt + (size_t)bh * DK * S_LEN + kbase;

    // Q fragments (A-operand), resident all kernel (scale pre-folded in gemm)
    half8 Aq[2][2];
#pragma unroll
    for (int qs = 0; qs < 2; qs++)
#pragma unroll
        for (int ch = 0; ch < 2; ch++)
            Aq[qs][ch] = ldh8(&Qg[(qs * 16 + l15) * DK + ch * 32 + q4 * 8]);

    // staging slots within each 256-thread half
    int grow[2], gseg[2];
#pragma unroll
    for (int i = 0; i < 2; i++) {
        const int slot = i * 256 + t255;
        grow[i] = slot >> 3;
        gseg[i] = ((slot & 7) ^ (grow[i] & 7)) * 8;
    }

    // fragment base offsets (halfs) into swizzled Ks/Vs; full offset =
    // kb[ch] + jt*1024 (jt*1024 folds into the ds_read immediate)
    int kb[2];
#pragma unroll
    for (int ch = 0; ch < 2; ch++)
        kb[ch] = l15 * 64 + (((ch * 4 + q4) ^ (l15 & 7)) * 8);

    // mask word base: row (qb + q4*4), key-half offset folded in.
    // index per (qs,reg,jw) = qs*512 + reg*32 + jw
    const unsigned long long* mrow_p = mb + (size_t)(qb + q4 * 4) * (S_LEN / 64) + z * 16;

    floatx4 O[2][4];
#pragma unroll
    for (int qs = 0; qs < 2; qs++)
#pragma unroll
        for (int nt = 0; nt < 4; nt++) O[qs][nt] = (floatx4){0.f, 0.f, 0.f, 0.f};
    floatx4 lacc[2];
    lacc[0] = (floatx4){0.f, 0.f, 0.f, 0.f};
    lacc[1] = (floatx4){0.f, 0.f, 0.f, 0.f};

    half8 onesB;
#pragma unroll
    for (int i = 0; i < 8; i++) onesB[i] = (_Float16)1.0f;

    const bool evenlane = ((lane & 1) == 0);

    // prologue: stage K_0 then V_0   (FIFO: K,K,V,V)
#pragma unroll
    for (int i = 0; i < 2; i++) {
        const int lb = (i * 256 + w4 * 64) * 8;
        gld16(&Kg[(size_t)grow[i] * DK + gseg[i]], &Ks[z][lb]);
    }
#pragma unroll
    for (int i = 0; i < 2; i++) {
        const int lb = (i * 256 + w4 * 64) * 8;
        gld16(&Vg[(size_t)grow[i] * S_LEN + gseg[i]], &Vs[z][lb]);
    }

    for (int j0 = 0; j0 < 1024; j0 += 64) {
        const int jn = (j0 + 64) & 1023;   // wrap keeps vmcnt schedule uniform
        const int jw = j0 >> 6;

        // ---- K gate: my K_j landed (V_j may still fly); then block-wide ----
        __builtin_amdgcn_sched_barrier(0);
        asm volatile("s_waitcnt vmcnt(2)" ::: "memory");
        rawbar();

        // ---- QK + fused softmax (per-jt: only one floatx4 live) ----
#pragma unroll
        for (int qs = 0; qs < 2; qs++) {
            unsigned long long mw[4];
#pragma unroll
            for (int jt = 0; jt < 4; jt++) {
                floatx4 c = (floatx4){0.f, 0.f, 0.f, 0.f};
                __builtin_amdgcn_s_setprio(1);
                c = __builtin_amdgcn_mfma_f32_16x16x32_f16(
                    Aq[qs][0], ldh8(&Ks[z][jt * 1024 + kb[0]]), c, 0, 0, 0);
                c = __builtin_amdgcn_mfma_f32_16x16x32_f16(
                    Aq[qs][1], ldh8(&Ks[z][jt * 1024 + kb[1]]), c, 0, 0, 0);
                __builtin_amdgcn_s_setprio(0);
                if (jt == 0) {
#pragma unroll
                    for (int reg = 0; reg < 4; reg++)
                        mw[reg] = mrow_p[qs * 512 + reg * 32 + jw];
                }
#pragma unroll
                for (int reg = 0; reg < 4; reg++) {
                    const unsigned ttw =
                        (unsigned)(mw[reg] >> (jt >= 2 ? 32 : 0)) >> l15;
                    const unsigned sel = ttw & (1u << ((jt & 1) * 16));
                    float p = __builtin_amdgcn_exp2f(c[reg]);
                    p = sel ? p : EXPM1;
                    const float po = dpp_swap1(p);
                    if (evenlane) {
                        *(unsigned*)&Ps[w][(qs * 16 + q4 * 4 + reg) * 72 +
                                           jt * 16 + l15] =
                            __builtin_bit_cast(unsigned,
                                __builtin_amdgcn_cvt_pkrtz(p, po));
                    }
                }
            }
        }

        // ---- Ks consumed block-wide -> prefetch K_{j+1} (flies over PV) ----
        rawbar();
#pragma unroll
        for (int i = 0; i < 2; i++) {
            const int lb = (i * 256 + w4 * 64) * 8;
            gld16(&Kg[(size_t)(jn + grow[i]) * DK + gseg[i]], &Ks[z][lb]);
        }

        // ---- V gate: my V_j landed (K_{j+1} in flight); block-wide ----
        __builtin_amdgcn_sched_barrier(0);
        asm volatile("s_waitcnt vmcnt(2)" ::: "memory");
        rawbar();

        // ---- PV: O[qs] += P[qs] @ V ; Σp via all-ones B ----
#pragma unroll
        for (int qs = 0; qs < 2; qs++) {
            half8 Ap[2];
#pragma unroll
            for (int ch = 0; ch < 2; ch++)
                Ap[ch] = ldh8(&Ps[w][(qs * 16 + l15) * 72 + ch * 32 + q4 * 8]);
            __builtin_amdgcn_s_setprio(1);
            lacc[qs] = __builtin_amdgcn_mfma_f32_16x16x32_f16(Ap[0], onesB, lacc[qs], 0, 0, 0);
            lacc[qs] = __builtin_amdgcn_mfma_f32_16x16x32_f16(Ap[1], onesB, lacc[qs], 0, 0, 0);
#pragma unroll
            for (int nt = 0; nt < 4; nt++) {
                O[qs][nt] = __builtin_amdgcn_mfma_f32_16x16x32_f16(
                    Ap[0], ldh8(&Vs[z][nt * 1024 + kb[0]]), O[qs][nt], 0, 0, 0);
                O[qs][nt] = __builtin_amdgcn_mfma_f32_16x16x32_f16(
                    Ap[1], ldh8(&Vs[z][nt * 1024 + kb[1]]), O[qs][nt], 0, 0, 0);
            }
            __builtin_amdgcn_s_setprio(0);
        }

        // ---- Vs consumed block-wide -> prefetch V_{j+1} (flies over QK) ----
        rawbar();
#pragma unroll
        for (int i = 0; i < 2; i++) {
            const int lb = (i * 256 + w4 * 64) * 8;
            gld16(&Vg[(size_t)grow[i] * S_LEN + jn + gseg[i]], &Vs[z][lb]);
        }
    }
    __builtin_amdgcn_sched_barrier(0);

    // cross-half combine via LDS (reuse Ps region: all P reads are done;
    // the loop's final rawbar ordered the last PV reads before these writes)
    float* Obuf = (float*)&Ps[0][0];                  // [4][32][65] fp32, 33.3 KB
    if (z == 1) {
#pragma unroll
        for (int qs = 0; qs < 2; qs++)
#pragma unroll
            for (int reg = 0; reg < 4; reg++) {
                const int rl = w4 * 32 + qs * 16 + q4 * 4 + reg;
#pragma unroll
                for (int nt = 0; nt < 4; nt++)
                    Obuf[rl * 65 + nt * 16 + l15] = O[qs][nt][reg];
                if (l15 == 0) Obuf[rl * 65 + 64] = lacc[qs][reg];
            }
    }
    __syncthreads();
    if (z == 0) {
#pragma unroll
        for (int qs = 0; qs < 2; qs++)
#pragma unroll
            for (int reg = 0; reg < 4; reg++) {
                const int rl = w4 * 32 + qs * 16 + q4 * 4 + reg;
                const float inv = 1.0f / (lacc[qs][reg] + Obuf[rl * 65 + 64]);
                const int srow = qb + qs * 16 + q4 * 4 + reg;
                _Float16* Xrow = Xh + (size_t)(b * S_LEN + srow) * 1024 + h * DK;
#pragma unroll
                for (int nt = 0; nt < 4; nt++)
                    Xrow[nt * 16 + l15] =
                        (_Float16)((O[qs][nt][reg] + Obuf[rl * 65 + nt * 16 + l15]) * inv);
            }
    }
}

// ---------------------------------------------------------------------------
extern "C" void kernel_launch(void* const* d_in, const int* in_sizes, int n_in,
                              void* d_out, int out_size, void* d_ws, size_t ws_size,
                              hipStream_t stream) {
    const float* q  = (const float*)d_in[0];
    const float* k  = (const float*)d_in[1];
    const float* v  = (const float*)d_in[2];
    const int* mask = (const int*)d_in[3];
    const float* wq = (const float*)d_in[4];
    const float* bq = (const float*)d_in[5];
    const float* wk = (const float*)d_in[6];
    const float* bk = (const float*)d_in[7];
    const float* wv = (const float*)d_in[8];
    const float* bv = (const float*)d_in[9];
    const float* wo = (const float*)d_in[10];
    const float* bo = (const float*)d_in[11];
    float* out = (float*)d_out;

    char* ws = (char*)d_ws;
    const size_t MB = 1u << 20;
    _Float16* Wh   = (_Float16*)ws;                    // 4 x 2 MB (wq,wk,wv,wo)
    _Float16* Ah   = (_Float16*)(ws + 8 * MB);         // 3 x 8 MB (q,k,v fp16)
    _Float16* QKVh = (_Float16*)(ws + 32 * MB);        // 2 x 8 MB head-major (Q,K)
    _Float16* Vt   = (_Float16*)(ws + 56 * MB);        // 8 MB
    unsigned long long* mb = (unsigned long long*)(ws + 64 * MB);  // 512 KB
    _Float16* Xh   = Ah;                               // reuse q slot (8 MB)

    prep<<<dim3(4096, 8), 256, 0, stream>>>(q, k, v, wq, wk, wv, wo, mask,
                                            Ah, Wh, mb);

    gemm_f16<1><<<dim3(8, 32, 3), 256, 0, stream>>>(Ah, Wh, bq, bk, bv, QKVh, Vt);

    attn_mfma<<<dim3(16, 32), 512, 0, stream>>>(QKVh, QKVh + (size_t)M_ROWS * 1024,
                                                Vt, mb, Xh);

    gemm_f16<0><<<dim3(8, 32), 256, 0, stream>>>(Xh, Wh + (size_t)3 * 1024 * 1024,
                                                 bo, bo, bo, out, nullptr);
}